// Round 4
// baseline (716.743 us; speedup 1.0000x reference)
//
#include <hip/hip_runtime.h>
#include <cmath>

typedef unsigned short u16;
typedef unsigned int   u32;
typedef short bhalf8 __attribute__((ext_vector_type(8)));
typedef float fx4    __attribute__((ext_vector_type(4)));

#define B_   4
#define S_   1024
#define D_   1024
#define H_   16
#define HD_  64
#define FF_  4096
#define NTOK (B_*S_)
#define QKVW 3072

__device__ __forceinline__ float b2f(u16 u) {
    u32 x = ((u32)u) << 16;
    return __uint_as_float(x);
}
__device__ __forceinline__ u16 f2b(float f) {
    u32 u = __float_as_uint(f);
    u32 r = (u + 0x7fffu + ((u >> 16) & 1u)) >> 16;
    return (u16)r;
}
// fast tanh: 1 - 2/(e^2x + 1); inf-safe at both ends, ~1e-7 abs err
__device__ __forceinline__ float ftanh(float x) {
    float e = __expf(2.f * x);
    return 1.f - 2.f / (e + 1.f);
}

// async global->LDS, 16B per lane; LDS dest = wave-uniform base + lane*16
#define GLDS16(g, l) __builtin_amdgcn_global_load_lds( \
    (const __attribute__((address_space(1))) void*)(g), \
    (__attribute__((address_space(3))) void*)(l), 16, 0, 0)

template <int N> __device__ __forceinline__ void waitvm() {
    if constexpr (N == 8) asm volatile("s_waitcnt vmcnt(8)" ::: "memory");
    else if constexpr (N == 6) asm volatile("s_waitcnt vmcnt(6)" ::: "memory");
    else if constexpr (N == 4) asm volatile("s_waitcnt vmcnt(4)" ::: "memory");
    else if constexpr (N == 3) asm volatile("s_waitcnt vmcnt(3)" ::: "memory");
    else if constexpr (N == 2) asm volatile("s_waitcnt vmcnt(2)" ::: "memory");
    else asm volatile("s_waitcnt vmcnt(0)" ::: "memory");
}

// ---------------------------------------------------------------------------
// Grid swizzle: XCD-chunked (bijective when nwg%8==0) + 8-row supertiles.
// ---------------------------------------------------------------------------
__device__ __forceinline__ void tile_swz(int gx, int gy, int& bx, int& by) {
    int bid = blockIdx.x;
    int nwg = gx * gy;
    if (((nwg | gy) & 7) == 0) {
        int chunk = nwg >> 3;
        int wg = (bid & 7) * chunk + (bid >> 3);
        int tps = gx << 3;
        int sup = wg / tps, rem = wg % tps;
        bx = rem >> 3;
        by = (sup << 3) + (rem & 7);
    } else {
        bx = bid % gx; by = bid / gx;
    }
}

// ---------------------------------------------------------------------------
// Weight convert + transpose: f32 [K,N] -> bf16 [N,K] tiles of 64x64.
// ---------------------------------------------------------------------------
__global__ __launch_bounds__(256) void cvt_t_k(const float* __restrict__ w0, const float* __restrict__ w1,
                                               const float* __restrict__ w2, const float* __restrict__ w3,
                                               const float* __restrict__ W1p, const float* __restrict__ J1p,
                                               const float* __restrict__ W2p, const float* __restrict__ J2p,
                                               u16* __restrict__ dst) {
    __shared__ u16 L[64][65];
    int bid = blockIdx.x, tid = threadIdx.x;
    const float* src; size_t dbase; int Kd, Nd, tk, tn;
    if (bid < 1024)      { int m = bid >> 8, t = bid & 255;
                           src = m == 0 ? w0 : m == 1 ? w1 : m == 2 ? w2 : w3;
                           dbase = (size_t)m << 20; Kd = 1024; Nd = 1024; tk = t >> 4; tn = t & 15; }
    else if (bid < 2048) { int t = bid - 1024; src = W1p; dbase = (size_t)4  << 20; Kd = 1024; Nd = 4096; tk = t >> 6; tn = t & 63; }
    else if (bid < 3072) { int t = bid - 2048; src = J1p; dbase = (size_t)8  << 20; Kd = 1024; Nd = 4096; tk = t >> 6; tn = t & 63; }
    else if (bid < 4096) { int t = bid - 3072; src = W2p; dbase = (size_t)12 << 20; Kd = 4096; Nd = 1024; tk = t >> 4; tn = t & 15; }
    else                 { int t = bid - 4096; src = J2p; dbase = (size_t)16 << 20; Kd = 4096; Nd = 1024; tk = t >> 4; tn = t & 15; }
    int k0 = tk * 64, n0 = tn * 64;
    int r = tid >> 2, c4 = (tid & 3) * 16;
    #pragma unroll
    for (int p = 0; p < 4; ++p) {
        float4 v = *(const float4*)&src[(size_t)(k0 + r) * Nd + n0 + c4 + p * 4];
        L[r][c4 + p * 4 + 0] = f2b(v.x);
        L[r][c4 + p * 4 + 1] = f2b(v.y);
        L[r][c4 + p * 4 + 2] = f2b(v.z);
        L[r][c4 + p * 4 + 3] = f2b(v.w);
    }
    __syncthreads();
    u16 o[16];
    #pragma unroll
    for (int j = 0; j < 16; ++j) o[j] = L[c4 + j][r];
    *(uint4*)&dst[dbase + (size_t)(n0 + r) * Kd + k0 + c4]     = *(uint4*)&o[0];
    *(uint4*)&dst[dbase + (size_t)(n0 + r) * Kd + k0 + c4 + 8] = *(uint4*)&o[8];
}

// elementwise tanh over bf16 buffer, 8 elems/thread (in-place safe)
__global__ __launch_bounds__(256) void tanh_k(const u16* __restrict__ in, u16* __restrict__ outb) {
    size_t idx = ((size_t)blockIdx.x * 256 + threadIdx.x) * 8;
    uint4 v = *(const uint4*)&in[idx];
    const u16* p = (const u16*)&v;
    u16 o[8];
    #pragma unroll
    for (int j = 0; j < 8; ++j) o[j] = f2b(ftanh(b2f(p[j])));
    *(uint4*)&outb[idx] = *(uint4*)o;
}

// ---------------------------------------------------------------------------
// gemmP: 8-wave (512 thr) pipelined MFMA GEMM, 3-stage circular LDS buffer,
// BK=32. C[M,N] = A[M,K] @ Bt[N,K]^T + bias.
//   EPI 0: store bf16(acc+bias)
//   EPI 1: store f32(acc+bias+resid)
//   EPI 2: ht=Cout[idx]; Cout=bf16(ht+0.5*acc*ftanh(ht))   (QBNN combine)
//   SEG:   bias segmented per 1024 cols (fused QKV)
// Schedule per iter t (slot sl=t%3):
//   STAGE(t+2 -> slot (t+2)%3)     // slot freed at t-1's read barrier
//   vmcnt(2*(IA+IB))               // stale wait: slot-t loads (2 iters old)
//   barrier                        // all waves' slot-t loads landed
//   ds_read frags; lgkmcnt(0); sched_barrier; barrier  // slot-t reads done
//   setprio(1); MFMA cluster; setprio(0)   // overlaps next iter's stage issue
// LDS swizzle: source col chunk ^= (row>>1)&3 (64B row stride -> banks repeat
// every 2 rows); reads use chunk q ^ (mr>>1)&3. Verified 0 conflicts (R3).
// ---------------------------------------------------------------------------
template <int BM, int BN, int WM, int WN, int EPI, bool SEG>
__global__ __launch_bounds__(512, 2) void gemmP(const u16* __restrict__ A,
                                                const u16* __restrict__ Bt,
                                                const float* __restrict__ bA,
                                                const float* __restrict__ bB,
                                                const float* __restrict__ bC,
                                                const float* __restrict__ resid,
                                                void* __restrict__ Cout,
                                                int M, int N, int K) {
    constexpr int IA = BM / 128;          // gload_lds per wave for A half
    constexpr int IB = BN / 128;
    constexpr int NWN = BN / WN;          // waves along N
    constexpr int FM = WM / 16, FN = WN / 16;
    __shared__ u16 As[3][BM * 32];
    __shared__ u16 Bs[3][BN * 32];

    const int tid = threadIdx.x;
    const int w = tid >> 6, ln = tid & 63;
    const int q = ln >> 4, mr = ln & 15;
    const int wmi = w / NWN, wni = w % NWN;
    int bx, by;
    tile_swz(N / BN, M / BM, bx, by);
    const int m0 = by * BM, n0 = bx * BN;

    const int lr = ln >> 2;                       // staging row-in-16
    const int sc = 8 * ((ln & 3) ^ ((ln >> 3) & 3));  // pre-swizzled src chunk
    const int qx8 = 8 * (q ^ ((mr >> 1) & 3));        // read chunk

    const u16* aA[IA];
    const u16* aB[IB];
    #pragma unroll
    for (int i = 0; i < IA; ++i)
        aA[i] = A + (size_t)(m0 + 16 * (w + 8 * i) + lr) * K + sc;
    #pragma unroll
    for (int i = 0; i < IB; ++i)
        aB[i] = Bt + (size_t)(n0 + 16 * (w + 8 * i) + lr) * K + sc;

    fx4 acc[FM][FN];
    #pragma unroll
    for (int i = 0; i < FM; ++i)
        #pragma unroll
        for (int j = 0; j < FN; ++j) acc[i][j] = (fx4){0.f, 0.f, 0.f, 0.f};

#define GP_STAGE(slot, kk) do { \
        _Pragma("unroll") \
        for (int i = 0; i < IA; ++i) GLDS16(aA[i] + (kk), &As[slot][(16 * (w + 8 * i)) * 32]); \
        _Pragma("unroll") \
        for (int i = 0; i < IB; ++i) GLDS16(aB[i] + (kk), &Bs[slot][(16 * (w + 8 * i)) * 32]); \
    } while (0)

    const int NT = K >> 5;
    GP_STAGE(0, 0);
    GP_STAGE(1, 32);
    int sl = 0, st = 2;
    for (int t = 0; t < NT; ++t) {
        if (t + 2 < NT) {
            GP_STAGE(st, (t + 2) << 5);
            waitvm<2 * (IA + IB)>();
        } else if (t + 1 < NT) {
            waitvm<IA + IB>();
        } else {
            waitvm<0>();
        }
        __builtin_amdgcn_sched_barrier(0);
        __builtin_amdgcn_s_barrier();
        __builtin_amdgcn_sched_barrier(0);

        bhalf8 afr[FM], bfr[FN];
        const u16* Ap = &As[sl][0];
        const u16* Bp = &Bs[sl][0];
        #pragma unroll
        for (int fm = 0; fm < FM; ++fm)
            afr[fm] = *(const bhalf8*)&Ap[(wmi * WM + fm * 16 + mr) * 32 + qx8];
        #pragma unroll
        for (int fn = 0; fn < FN; ++fn)
            bfr[fn] = *(const bhalf8*)&Bp[(wni * WN + fn * 16 + mr) * 32 + qx8];
        asm volatile("s_waitcnt lgkmcnt(0)" ::: "memory");
        __builtin_amdgcn_sched_barrier(0);
        __builtin_amdgcn_s_barrier();
        __builtin_amdgcn_sched_barrier(0);

        __builtin_amdgcn_s_setprio(1);
        #pragma unroll
        for (int fm = 0; fm < FM; ++fm)
            #pragma unroll
            for (int fn = 0; fn < FN; ++fn)
                acc[fm][fn] = __builtin_amdgcn_mfma_f32_16x16x32_bf16(afr[fm], bfr[fn], acc[fm][fn], 0, 0, 0);
        __builtin_amdgcn_s_setprio(0);

        sl = sl == 2 ? 0 : sl + 1;
        st = st == 2 ? 0 : st + 1;
    }
#undef GP_STAGE

    #pragma unroll
    for (int fn = 0; fn < FN; ++fn) {
        int col = n0 + wni * WN + fn * 16 + mr;
        float bs;
        if (SEG) {
            const float* bp = col < 1024 ? bA : (col < 2048 ? bB : bC);
            bs = bp[col & 1023];
        } else {
            bs = bA ? bA[col] : 0.f;
        }
        #pragma unroll
        for (int fm = 0; fm < FM; ++fm) {
            #pragma unroll
            for (int r = 0; r < 4; ++r) {
                int row    = m0 + wmi * WM + fm * 16 + q * 4 + r;
                size_t idx = (size_t)row * N + col;
                float v    = acc[fm][fn][r] + bs;
                if (EPI == 0) {
                    ((u16*)Cout)[idx] = f2b(v);
                } else if (EPI == 1) {
                    ((float*)Cout)[idx] = v + resid[idx];
                } else {
                    float ht = b2f(((u16*)Cout)[idx]);
                    ((u16*)Cout)[idx] = f2b(ht + 0.5f * v * ftanh(ht));
                }
            }
        }
    }
}

// ---------------------------------------------------------------------------
// LayerNorm over f32 input rows -> bf16 out.
// ---------------------------------------------------------------------------
__global__ __launch_bounds__(256) void ln_k(const float* __restrict__ xin,
                                            const float* __restrict__ g,
                                            const float* __restrict__ bb,
                                            u16* __restrict__ out, int W) {
    __shared__ float red[8], red2[8], stats[2];
    int row = blockIdx.x, tid = threadIdx.x;
    float s = 0.f, ss = 0.f;
    for (int c = tid; c < W; c += 256) {
        float v = xin[(size_t)row * W + c];
        s += v; ss += v * v;
    }
    #pragma unroll
    for (int off = 32; off; off >>= 1) { s += __shfl_xor(s, off); ss += __shfl_xor(ss, off); }
    int wave = tid >> 6, lane = tid & 63;
    if (lane == 0) { red[wave] = s; red2[wave] = ss; }
    __syncthreads();
    if (tid == 0) {
        float S = 0.f, SS = 0.f;
        for (int w2 = 0; w2 < 4; ++w2) { S += red[w2]; SS += red2[w2]; }
        float mu = S / W;
        stats[0] = mu;
        stats[1] = rsqrtf(SS / W - mu * mu + 1e-5f);
    }
    __syncthreads();
    float mu = stats[0], rs = stats[1];
    for (int c = tid; c < W; c += 256)
        out[(size_t)row * W + c] = f2b((xin[(size_t)row * W + c] - mu) * rs * g[c] + bb[c]);
}

// ---------------------------------------------------------------------------
// LN + exact GELU over bf16 rows u. RES: add f32 resid. OUT_F32: f32 out.
// ---------------------------------------------------------------------------
template <bool RES, bool OUT_F32>
__global__ __launch_bounds__(256) void lngelu_k(const u16* __restrict__ u,
                                                const float* __restrict__ g,
                                                const float* __restrict__ be,
                                                const float* __restrict__ resid,
                                                void* __restrict__ out, int W) {
    __shared__ float ub[4096];
    __shared__ float red[8], red2[8], stats[2];
    int row = blockIdx.x, tid = threadIdx.x;
    float s = 0.f, ss = 0.f;
    for (int c = tid; c < W; c += 256) {
        float v = b2f(u[(size_t)row * W + c]);
        ub[c] = v; s += v; ss += v * v;
    }
    #pragma unroll
    for (int off = 32; off; off >>= 1) { s += __shfl_xor(s, off); ss += __shfl_xor(ss, off); }
    int wave = tid >> 6, lane = tid & 63;
    if (lane == 0) { red[wave] = s; red2[wave] = ss; }
    __syncthreads();
    if (tid == 0) {
        float S = 0.f, SS = 0.f;
        for (int w2 = 0; w2 < 4; ++w2) { S += red[w2]; SS += red2[w2]; }
        float mu = S / W;
        stats[0] = mu;
        stats[1] = rsqrtf(SS / W - mu * mu + 1e-5f);
    }
    __syncthreads();
    float mu = stats[0], rs = stats[1];
    for (int c = tid; c < W; c += 256) {
        float v = (ub[c] - mu) * rs * g[c] + be[c];
        float y = 0.5f * v * (1.f + erff(v * 0.70710678118654752f));
        if (RES) y += resid[(size_t)row * W + c];
        if (OUT_F32) ((float*)out)[(size_t)row * W + c] = y;
        else         ((u16*)out)[(size_t)row * W + c] = f2b(y);
    }
}

// ---------------------------------------------------------------------------
// Qaug[B,H,S,128]: [0:64]=Q/8, [64:128]=lam*(tanh(Q)@J[h]).
// ---------------------------------------------------------------------------
__global__ __launch_bounds__(256) void aug_q_k(const u16* __restrict__ QKV,
                                               const float* __restrict__ J,
                                               const float* __restrict__ lamp,
                                               u16* __restrict__ QA) {
    __shared__ float Jl[64][68];
    __shared__ float Tq[64][65];
    int blk = blockIdx.x;
    int bh = blk >> 4, st = blk & 15;
    int b = bh >> 4, h = bh & 15;
    int s0 = st * 64;
    int tid = threadIdx.x;
    float lam = lamp[0];

    for (int i = tid; i < 4096; i += 256)
        Jl[i >> 6][i & 63] = J[h * 4096 + i];
    for (int i = tid; i < 4096; i += 256) {
        int r = i >> 6, c = i & 63;
        float v  = b2f(QKV[(size_t)(b * S_ + s0 + r) * QKVW + h * 64 + c]);
        Tq[r][c] = ftanh(v);
        QA[((size_t)(bh * S_ + s0 + r)) * 128 + c] = f2b(v * 0.125f);  // /sqrt(64)
    }
    __syncthreads();

    int r = tid >> 2, c0 = (tid & 3) * 16;
    float acc[16];
    #pragma unroll
    for (int j = 0; j < 16; ++j) acc[j] = 0.f;
    for (int k = 0; k < 64; ++k) {
        float a = Tq[r][k];
        #pragma unroll
        for (int j4 = 0; j4 < 4; ++j4) {
            float4 jv = *(const float4*)&Jl[k][c0 + j4 * 4];
            acc[j4 * 4 + 0] += a * jv.x;
            acc[j4 * 4 + 1] += a * jv.y;
            acc[j4 * 4 + 2] += a * jv.z;
            acc[j4 * 4 + 3] += a * jv.w;
        }
    }
    size_t orow = ((size_t)(bh * S_ + s0 + r)) * 128 + 64 + c0;
    #pragma unroll
    for (int j = 0; j < 16; ++j) QA[orow + j] = f2b(lam * acc[j]);
}

// Kaug[B,H,S,128]: [0:64]=K, [64:128]=tanh(K).
__global__ __launch_bounds__(256) void aug_k_k(const u16* __restrict__ QKV,
                                               u16* __restrict__ KA) {
    int idx = blockIdx.x * 256 + threadIdx.x;  // < B*S*D
    int d = idx & (D_ - 1);
    int bs = idx >> 10;
    int h = d >> 6, hd = d & 63;
    int b = bs >> 10, si = bs & (S_ - 1);
    u16 v      = QKV[(size_t)bs * QKVW + 1024 + d];
    size_t row = (size_t)((b * H_ + h) * S_ + si);
    KA[row * 128 + hd]      = v;
    KA[row * 128 + 64 + hd] = f2b(ftanh(b2f(v)));
}

// ---------------------------------------------------------------------------
// MFMA flash attention. V in QKV cols [2048,3072).
// ---------------------------------------------------------------------------
#define QS_STRIDE 136
#define PS_STRIDE 72
__global__ __launch_bounds__(256) void attn_k(const u16* __restrict__ QA,
                                              const u16* __restrict__ KA,
                                              const u16* __restrict__ QKV,
                                              u16* __restrict__ out) {
    __shared__ u16 Qs[64 * QS_STRIDE];
    __shared__ u16 Ks[64 * QS_STRIDE];
    __shared__ u16 Vt[64 * PS_STRIDE];
    __shared__ u16 Ps[4 * 16 * PS_STRIDE];

    const int tid  = threadIdx.x;
    const int w    = tid >> 6, lane = tid & 63;
    const int q    = lane >> 4, mr = lane & 15;
    const int bh   = blockIdx.x >> 4;
    const int qt   = blockIdx.x & 15;
    const int b    = bh >> 4, h = bh & 15;

    #pragma unroll
    for (int p = 0; p < 4; ++p) {
        int idx = p * 2048 + tid * 8;
        int row = idx >> 7, col = idx & 127;
        uint4 v4 = *(const uint4*)&QA[((size_t)(bh * S_ + qt * 64 + row)) * 128 + col];
        *(uint4*)&Qs[row * QS_STRIDE + col] = v4;
    }

    fx4 zero = {0.f, 0.f, 0.f, 0.f};
    fx4 O[4] = {zero, zero, zero, zero};
    float m[4]  = {-3e38f, -3e38f, -3e38f, -3e38f};
    float l[4]  = {0.f, 0.f, 0.f, 0.f};

    for (int kt = 0; kt < 16; ++kt) {
        #pragma unroll
        for (int p = 0; p < 4; ++p) {
            int idx = p * 2048 + tid * 8;
            int row = idx >> 7, col = idx & 127;
            uint4 v4 = *(const uint4*)&KA[((size_t)(bh * S_ + kt * 64 + row)) * 128 + col];
            *(uint4*)&Ks[row * QS_STRIDE + col] = v4;
        }
        #pragma unroll
        for (int p = 0; p < 2; ++p) {
            int idx = p * 2048 + tid * 8;
            int key = idx >> 6, d0 = idx & 63;
            uint4 v4 = *(const uint4*)&QKV[((size_t)(b * S_ + kt * 64 + key)) * QKVW + 2048 + h * 64 + d0];
            const u16* vp = (const u16*)&v4;
            #pragma unroll
            for (int j = 0; j < 8; ++j) Vt[(d0 + j) * PS_STRIDE + key] = vp[j];
        }
        __syncthreads();

        fx4 St[4] = {zero, zero, zero, zero};
        bhalf8 afr[4];
        #pragma unroll
        for (int ks = 0; ks < 4; ++ks)
            afr[ks] = *(const bhalf8*)&Qs[(w * 16 + mr) * QS_STRIDE + ks * 32 + q * 8];
        __builtin_amdgcn_s_setprio(1);
        #pragma unroll
        for (int nt = 0; nt < 4; ++nt) {
            #pragma unroll
            for (int ks = 0; ks < 4; ++ks) {
                bhalf8 bf = *(const bhalf8*)&Ks[(nt * 16 + mr) * QS_STRIDE + ks * 32 + q * 8];
                St[nt] = __builtin_amdgcn_mfma_f32_16x16x32_bf16(afr[ks], bf, St[nt], 0, 0, 0);
            }
        }
        __builtin_amdgcn_s_setprio(0);

        float alpha[4];
        #pragma unroll
        for (int r = 0; r < 4; ++r) {
            float mx = fmaxf(fmaxf(St[0][r], St[1][r]), fmaxf(St[2][r], St[3][r]));
            #pragma unroll
            for (int off = 8; off; off >>= 1) mx = fmaxf(mx, __shfl_xor(mx, off));
            float nm = fmaxf(m[r], mx);
            alpha[r] = __expf(m[r] - nm);
            m[r] = nm;
            float ps = 0.f;
            #pragma unroll
            for (int nt = 0; nt < 4; ++nt) {
                float p = __expf(St[nt][r] - nm);
                St[nt][r] = p;
                ps += p;
            }
            #pragma unroll
            for (int off = 8; off; off >>= 1) ps += __shfl_xor(ps, off);
            l[r] = l[r] * alpha[r] + ps;
        }
        #pragma unroll
        for (int nt = 0; nt < 4; ++nt) {
            #pragma unroll
            for (int r = 0; r < 4; ++r) {
                Ps[(w * 16 + q * 4 + r) * PS_STRIDE + nt * 16 + mr] = f2b(St[nt][r]);
                O[nt][r] *= alpha[r];
            }
        }

        __builtin_amdgcn_s_setprio(1);
        #pragma unroll
        for (int ks = 0; ks < 2; ++ks) {
            bhalf8 pa = *(const bhalf8*)&Ps[(w * 16 + mr) * PS_STRIDE + ks * 32 + q * 8];
            #pragma unroll
            for (int nt = 0; nt < 4; ++nt) {
                bhalf8 bf = *(const bhalf8*)&Vt[(nt * 16 + mr) * PS_STRIDE + ks * 32 + q * 8];
                O[nt] = __builtin_amdgcn_mfma_f32_16x16x32_bf16(pa, bf, O[nt], 0, 0, 0);
            }
        }
        __builtin_amdgcn_s_setprio(0);
        __syncthreads();
    }

    #pragma unroll
    for (int nt = 0; nt < 4; ++nt) {
        int d = nt * 16 + mr;
        #pragma unroll
        for (int r = 0; r < 4; ++r) {
            int row = qt * 64 + w * 16 + q * 4 + r;
            out[((size_t)(b * S_ + row)) * D_ + h * 64 + d] = f2b(O[nt][r] / l[r]);
        }
    }
}

// ---------------------------------------------------------------------------
// Workspace (104 MB):
//   [  0, 40)  WB: bf16 weights TRANSPOSED [N,K] — live whole launch
//   [ 40, 48)  XN(1-2) -> AT(4-5) -> U2(8-9)
//   [ 48, 72)  QKV fused (2-4) -> Hb[48,56)(6-7) + X2 f32[56,72)(5-9)
//   [ 72,104)  QA[72,88)+KA[88,104)(3-4) -> U1(7-9)
// ---------------------------------------------------------------------------
extern "C" void kernel_launch(void* const* d_in, const int* in_sizes, int n_in,
                              void* d_out, int out_size, void* d_ws, size_t ws_size,
                              hipStream_t stream) {
    const float* x      = (const float*)d_in[0];
    const float* wq     = (const float*)d_in[1];
    const float* bq     = (const float*)d_in[2];
    const float* wk     = (const float*)d_in[3];
    const float* bk     = (const float*)d_in[4];
    const float* wv     = (const float*)d_in[5];
    const float* bv     = (const float*)d_in[6];
    const float* wo     = (const float*)d_in[7];
    const float* bo     = (const float*)d_in[8];
    const float* Jattn  = (const float*)d_in[9];
    const float* lamA   = (const float*)d_in[10];
    const float* g_attn = (const float*)d_in[11];
    const float* b_attn = (const float*)d_in[12];
    const float* W1     = (const float*)d_in[13];
    const float* b1     = (const float*)d_in[14];
    const float* J1     = (const float*)d_in[15];
    const float* g1     = (const float*)d_in[17];
    const float* be1    = (const float*)d_in[18];
    const float* W2     = (const float*)d_in[19];
    const float* b2     = (const float*)d_in[20];
    const float* J2     = (const float*)d_in[21];
    const float* g2     = (const float*)d_in[23];
    const float* be2    = (const float*)d_in[24];
    const float* g_ffn  = (const float*)d_in[25];
    const float* b_ffn  = (const float*)d_in[26];
    float* out = (float*)d_out;
    (void)in_sizes; (void)n_in; (void)out_size; (void)ws_size;

    char* wsp = (char*)d_ws;
    const size_t MB = 1u << 20;
    u16* WB = (u16*)(wsp);
    const u16* qkvT = WB;                        // wq|wk|wv transposed, [3072,1024]
    const u16* woT  = WB + ((size_t)3 << 20);
    const u16* W1T  = WB + ((size_t)4 << 20);
    const u16* J1T  = WB + ((size_t)8 << 20);
    const u16* W2T  = WB + ((size_t)12 << 20);
    const u16* J2T  = WB + ((size_t)16 << 20);
    u16*   XN   = (u16*)(wsp + 40 * MB);
    u16*   AT   = (u16*)(wsp + 40 * MB);
    u16*   U2   = (u16*)(wsp + 40 * MB);
    u16*   QKVb = (u16*)(wsp + 48 * MB);
    u16*   Hb   = (u16*)(wsp + 48 * MB);
    float* X2   = (float*)(wsp + 56 * MB);
    u16*   QA   = (u16*)(wsp + 72 * MB);
    u16*   KA   = (u16*)(wsp + 88 * MB);
    u16*   U1   = (u16*)(wsp + 72 * MB);

    dim3 blk(256), blk5(512);
    // 0) weights f32 -> bf16, transposed to [N,K]
    cvt_t_k<<<5120, blk, 0, stream>>>(wq, wk, wv, wo, W1, J1, W2, J2, WB);
    // 1) attention pre-norm
    ln_k<<<NTOK, blk, 0, stream>>>(x, g_attn, b_attn, XN, D_);
    // 2) fused QKV projection [NTOK,3072]: BM=128,BN=256 -> grid 384, 2 blk/CU
    gemmP<128, 256, 64, 64, 0, true><<<(QKVW / 256) * (NTOK / 128), blk5, 0, stream>>>(
        XN, qkvT, bq, bk, bv, nullptr, QKVb, NTOK, QKVW, D_);
    // 3) augmented heads
    aug_q_k<<<B_ * H_ * (S_ / 64), blk, 0, stream>>>(QKVb, Jattn, lamA, QA);
    aug_k_k<<<(NTOK * D_) / 256, blk, 0, stream>>>(QKVb, KA);
    // 4) MFMA flash attention
    attn_k<<<B_ * H_ * (S_ / 64), blk, 0, stream>>>(QA, KA, QKVb, AT);
    // 5) output projection + residual -> f32 trunk X2 (128x128 -> grid 256)
    gemmP<128, 128, 64, 32, 1, false><<<(D_ / 128) * (NTOK / 128), blk5, 0, stream>>>(
        AT, woT, bo, nullptr, nullptr, x, X2, NTOK, D_, D_);
    // 6) ffn pre-norm
    ln_k<<<NTOK, blk, 0, stream>>>(X2, g_ffn, b_ffn, Hb, D_);
    // 7) QBNN layer 1 (3-pass): W1 -> U1; tanh(Hb) in place; J1 RMW; LN+GELU
    gemmP<256, 256, 128, 64, 0, false><<<(FF_ / 256) * (NTOK / 256), blk5, 0, stream>>>(
        Hb, W1T, b1, nullptr, nullptr, nullptr, U1, NTOK, FF_, D_);
    tanh_k<<<(NTOK * D_) / 2048, blk, 0, stream>>>(Hb, Hb);
    gemmP<256, 256, 128, 64, 2, false><<<(FF_ / 256) * (NTOK / 256), blk5, 0, stream>>>(
        Hb, J1T, nullptr, nullptr, nullptr, nullptr, U1, NTOK, FF_, D_);
    lngelu_k<false, false><<<NTOK, blk, 0, stream>>>(U1, g1, be1, nullptr, U1, FF_);
    // 8) QBNN layer 2 (3-pass): W2 -> U2; tanh(U1) in place; J2 RMW
    gemmP<128, 128, 64, 32, 0, false><<<(D_ / 128) * (NTOK / 128), blk5, 0, stream>>>(
        U1, W2T, b2, nullptr, nullptr, nullptr, U2, NTOK, D_, FF_);
    tanh_k<<<(NTOK * FF_) / 2048, blk, 0, stream>>>(U1, U1);
    gemmP<128, 128, 64, 32, 2, false><<<(D_ / 128) * (NTOK / 128), blk5, 0, stream>>>(
        U1, J2T, nullptr, nullptr, nullptr, nullptr, U2, NTOK, D_, FF_);
    lngelu_k<true, true><<<NTOK, blk, 0, stream>>>(U2, g2, be2, X2, out, D_);
}

// Round 5
// 656.790 us; speedup vs baseline: 1.0913x; 1.0913x over previous
//
#include <hip/hip_runtime.h>
#include <cmath>

typedef unsigned short u16;
typedef unsigned int   u32;
typedef short bhalf8 __attribute__((ext_vector_type(8)));
typedef float fx4    __attribute__((ext_vector_type(4)));

#define B_   4
#define S_   1024
#define D_   1024
#define H_   16
#define HD_  64
#define FF_  4096
#define NTOK (B_*S_)
#define QKVW 3072

__device__ __forceinline__ float b2f(u16 u) {
    u32 x = ((u32)u) << 16;
    return __uint_as_float(x);
}
__device__ __forceinline__ u16 f2b(float f) {
    u32 u = __float_as_uint(f);
    u32 r = (u + 0x7fffu + ((u >> 16) & 1u)) >> 16;
    return (u16)r;
}
// fast tanh: 1 - 2/(e^2x + 1); inf-safe at both ends
__device__ __forceinline__ float ftanh(float x) {
    float e = __expf(2.f * x);
    return 1.f - 2.f / (e + 1.f);
}

// async global->LDS, 16B per lane; LDS dest = wave-uniform base + lane*16
#define GLDS16(g, l) __builtin_amdgcn_global_load_lds( \
    (const __attribute__((address_space(1))) void*)(g), \
    (__attribute__((address_space(3))) void*)(l), 16, 0, 0)

template <int N> __device__ __forceinline__ void waitvm() {
    if constexpr (N == 8) asm volatile("s_waitcnt vmcnt(8)" ::: "memory");
    else if constexpr (N == 6) asm volatile("s_waitcnt vmcnt(6)" ::: "memory");
    else if constexpr (N == 4) asm volatile("s_waitcnt vmcnt(4)" ::: "memory");
    else if constexpr (N == 3) asm volatile("s_waitcnt vmcnt(3)" ::: "memory");
    else if constexpr (N == 2) asm volatile("s_waitcnt vmcnt(2)" ::: "memory");
    else asm volatile("s_waitcnt vmcnt(0)" ::: "memory");
}

// ---------------------------------------------------------------------------
// Grid swizzle: XCD-chunked (bijective when nwg%8==0) + 8-row supertiles.
// ---------------------------------------------------------------------------
__device__ __forceinline__ void tile_swz(int gx, int gy, int& bx, int& by) {
    int bid = blockIdx.x;
    int nwg = gx * gy;
    if (((nwg | gy) & 7) == 0) {
        int chunk = nwg >> 3;
        int wg = (bid & 7) * chunk + (bid >> 3);
        int tps = gx << 3;
        int sup = wg / tps, rem = wg % tps;
        bx = rem >> 3;
        by = (sup << 3) + (rem & 7);
    } else {
        bx = bid % gx; by = bid / gx;
    }
}

// ---------------------------------------------------------------------------
// Weight convert + transpose: f32 [K,N] -> bf16 [N,K] tiles of 64x64.
// ---------------------------------------------------------------------------
__global__ __launch_bounds__(256) void cvt_t_k(const float* __restrict__ w0, const float* __restrict__ w1,
                                               const float* __restrict__ w2, const float* __restrict__ w3,
                                               const float* __restrict__ W1p, const float* __restrict__ J1p,
                                               const float* __restrict__ W2p, const float* __restrict__ J2p,
                                               u16* __restrict__ dst) {
    __shared__ u16 L[64][65];
    int bid = blockIdx.x, tid = threadIdx.x;
    const float* src; size_t dbase; int Kd, Nd, tk, tn;
    if (bid < 1024)      { int m = bid >> 8, t = bid & 255;
                           src = m == 0 ? w0 : m == 1 ? w1 : m == 2 ? w2 : w3;
                           dbase = (size_t)m << 20; Kd = 1024; Nd = 1024; tk = t >> 4; tn = t & 15; }
    else if (bid < 2048) { int t = bid - 1024; src = W1p; dbase = (size_t)4  << 20; Kd = 1024; Nd = 4096; tk = t >> 6; tn = t & 63; }
    else if (bid < 3072) { int t = bid - 2048; src = J1p; dbase = (size_t)8  << 20; Kd = 1024; Nd = 4096; tk = t >> 6; tn = t & 63; }
    else if (bid < 4096) { int t = bid - 3072; src = W2p; dbase = (size_t)12 << 20; Kd = 4096; Nd = 1024; tk = t >> 4; tn = t & 15; }
    else                 { int t = bid - 4096; src = J2p; dbase = (size_t)16 << 20; Kd = 4096; Nd = 1024; tk = t >> 4; tn = t & 15; }
    int k0 = tk * 64, n0 = tn * 64;
    int r = tid >> 2, c4 = (tid & 3) * 16;
    #pragma unroll
    for (int p = 0; p < 4; ++p) {
        float4 v = *(const float4*)&src[(size_t)(k0 + r) * Nd + n0 + c4 + p * 4];
        L[r][c4 + p * 4 + 0] = f2b(v.x);
        L[r][c4 + p * 4 + 1] = f2b(v.y);
        L[r][c4 + p * 4 + 2] = f2b(v.z);
        L[r][c4 + p * 4 + 3] = f2b(v.w);
    }
    __syncthreads();
    u16 o[16];
    #pragma unroll
    for (int j = 0; j < 16; ++j) o[j] = L[c4 + j][r];
    *(uint4*)&dst[dbase + (size_t)(n0 + r) * Kd + k0 + c4]     = *(uint4*)&o[0];
    *(uint4*)&dst[dbase + (size_t)(n0 + r) * Kd + k0 + c4 + 8] = *(uint4*)&o[8];
}

// elementwise tanh over bf16 buffer, 8 elems/thread (in-place safe)
__global__ __launch_bounds__(256) void tanh_k(const u16* __restrict__ in, u16* __restrict__ outb) {
    size_t idx = ((size_t)blockIdx.x * 256 + threadIdx.x) * 8;
    uint4 v = *(const uint4*)&in[idx];
    const u16* p = (const u16*)&v;
    u16 o[8];
    #pragma unroll
    for (int j = 0; j < 8; ++j) o[j] = f2b(ftanh(b2f(p[j])));
    *(uint4*)&outb[idx] = *(uint4*)o;
}

// ---------------------------------------------------------------------------
// gemmP: 8-wave (512 thr) pipelined MFMA GEMM, 4-slot circular LDS buffer,
// prefetch depth 2, ONE barrier per K-step. BK=32.
// Hazard proof (slots=4, depth=2): stage target slot (t+2)%4 was last read at
// iter t-2; those reads retired before each wave issued its iter-t-2 MFMAs
// (data dep), hence before barrier t-1, which precedes the stage at iter t.
// Tile-t data landed: vmcnt(4) leaves <=2 groups outstanding -> group t
// retired for this wave; barrier t makes it true for all waves.
// LDS chunk-XOR swizzle as verified in R3 (0 conflicts).
// ---------------------------------------------------------------------------
template <int BM, int BN, int WM, int WN, int EPI, bool SEG>
__global__ __launch_bounds__(512, 2) void gemmP(const u16* __restrict__ A,
                                                const u16* __restrict__ Bt,
                                                const float* __restrict__ bA,
                                                const float* __restrict__ bB,
                                                const float* __restrict__ bC,
                                                const float* __restrict__ resid,
                                                void* __restrict__ Cout,
                                                int M, int N, int K) {
    constexpr int IA = BM / 128;
    constexpr int IB = BN / 128;
    constexpr int NWN = BN / WN;
    constexpr int FM = WM / 16, FN = WN / 16;
    __shared__ u16 As[4][BM * 32];
    __shared__ u16 Bs[4][BN * 32];

    const int tid = threadIdx.x;
    const int w = tid >> 6, ln = tid & 63;
    const int q = ln >> 4, mr = ln & 15;
    const int wmi = w / NWN, wni = w % NWN;
    int bx, by;
    tile_swz(N / BN, M / BM, bx, by);
    const int m0 = by * BM, n0 = bx * BN;

    const int lr = ln >> 2;
    const int sc = 8 * ((ln & 3) ^ ((ln >> 3) & 3));
    const int qx8 = 8 * (q ^ ((mr >> 1) & 3));

    const u16* aA[IA];
    const u16* aB[IB];
    #pragma unroll
    for (int i = 0; i < IA; ++i)
        aA[i] = A + (size_t)(m0 + 16 * (w + 8 * i) + lr) * K + sc;
    #pragma unroll
    for (int i = 0; i < IB; ++i)
        aB[i] = Bt + (size_t)(n0 + 16 * (w + 8 * i) + lr) * K + sc;

    fx4 acc[FM][FN];
    #pragma unroll
    for (int i = 0; i < FM; ++i)
        #pragma unroll
        for (int j = 0; j < FN; ++j) acc[i][j] = (fx4){0.f, 0.f, 0.f, 0.f};

#define GP_STAGE(slot, kk) do { \
        _Pragma("unroll") \
        for (int i = 0; i < IA; ++i) GLDS16(aA[i] + (kk), &As[slot][(16 * (w + 8 * i)) * 32]); \
        _Pragma("unroll") \
        for (int i = 0; i < IB; ++i) GLDS16(aB[i] + (kk), &Bs[slot][(16 * (w + 8 * i)) * 32]); \
    } while (0)

    const int NT = K >> 5;
    GP_STAGE(0, 0);
    GP_STAGE(1, 32);
    for (int t = 0; t < NT; ++t) {
        if (t + 2 < NT) {
            GP_STAGE((t + 2) & 3, (t + 2) << 5);
            waitvm<2 * (IA + IB)>();
        } else if (t + 1 < NT) {
            waitvm<IA + IB>();
        } else {
            waitvm<0>();
        }
        asm volatile("s_waitcnt lgkmcnt(0)" ::: "memory");
        __builtin_amdgcn_sched_barrier(0);
        __builtin_amdgcn_s_barrier();
        __builtin_amdgcn_sched_barrier(0);

        const int sl = t & 3;
        bhalf8 afr[FM], bfr[FN];
        const u16* Ap = &As[sl][0];
        const u16* Bp = &Bs[sl][0];
        #pragma unroll
        for (int fm = 0; fm < FM; ++fm)
            afr[fm] = *(const bhalf8*)&Ap[(wmi * WM + fm * 16 + mr) * 32 + qx8];
        #pragma unroll
        for (int fn = 0; fn < FN; ++fn)
            bfr[fn] = *(const bhalf8*)&Bp[(wni * WN + fn * 16 + mr) * 32 + qx8];

        __builtin_amdgcn_s_setprio(1);
        #pragma unroll
        for (int fm = 0; fm < FM; ++fm)
            #pragma unroll
            for (int fn = 0; fn < FN; ++fn)
                acc[fm][fn] = __builtin_amdgcn_mfma_f32_16x16x32_bf16(afr[fm], bfr[fn], acc[fm][fn], 0, 0, 0);
        __builtin_amdgcn_s_setprio(0);
    }
#undef GP_STAGE

    #pragma unroll
    for (int fn = 0; fn < FN; ++fn) {
        int col = n0 + wni * WN + fn * 16 + mr;
        float bs;
        if (SEG) {
            const float* bp = col < 1024 ? bA : (col < 2048 ? bB : bC);
            bs = bp[col & 1023];
        } else {
            bs = bA ? bA[col] : 0.f;
        }
        #pragma unroll
        for (int fm = 0; fm < FM; ++fm) {
            #pragma unroll
            for (int r = 0; r < 4; ++r) {
                int row    = m0 + wmi * WM + fm * 16 + q * 4 + r;
                size_t idx = (size_t)row * N + col;
                float v    = acc[fm][fn][r] + bs;
                if (EPI == 0) {
                    ((u16*)Cout)[idx] = f2b(v);
                } else if (EPI == 1) {
                    ((float*)Cout)[idx] = v + resid[idx];
                } else {
                    float ht = b2f(((u16*)Cout)[idx]);
                    ((u16*)Cout)[idx] = f2b(ht + 0.5f * v * ftanh(ht));
                }
            }
        }
    }
}

// ---------------------------------------------------------------------------
// LayerNorm over f32 input rows -> bf16 out.
// ---------------------------------------------------------------------------
__global__ __launch_bounds__(256) void ln_k(const float* __restrict__ xin,
                                            const float* __restrict__ g,
                                            const float* __restrict__ bb,
                                            u16* __restrict__ out, int W) {
    __shared__ float red[8], red2[8], stats[2];
    int row = blockIdx.x, tid = threadIdx.x;
    float s = 0.f, ss = 0.f;
    for (int c = tid; c < W; c += 256) {
        float v = xin[(size_t)row * W + c];
        s += v; ss += v * v;
    }
    #pragma unroll
    for (int off = 32; off; off >>= 1) { s += __shfl_xor(s, off); ss += __shfl_xor(ss, off); }
    int wave = tid >> 6, lane = tid & 63;
    if (lane == 0) { red[wave] = s; red2[wave] = ss; }
    __syncthreads();
    if (tid == 0) {
        float S = 0.f, SS = 0.f;
        for (int w2 = 0; w2 < 4; ++w2) { S += red[w2]; SS += red2[w2]; }
        float mu = S / W;
        stats[0] = mu;
        stats[1] = rsqrtf(SS / W - mu * mu + 1e-5f);
    }
    __syncthreads();
    float mu = stats[0], rs = stats[1];
    for (int c = tid; c < W; c += 256)
        out[(size_t)row * W + c] = f2b((xin[(size_t)row * W + c] - mu) * rs * g[c] + bb[c]);
}

// ---------------------------------------------------------------------------
// LN + exact GELU over bf16 rows u. RES: add f32 resid. OUT_F32: f32 out.
// ---------------------------------------------------------------------------
template <bool RES, bool OUT_F32>
__global__ __launch_bounds__(256) void lngelu_k(const u16* __restrict__ u,
                                                const float* __restrict__ g,
                                                const float* __restrict__ be,
                                                const float* __restrict__ resid,
                                                void* __restrict__ out, int W) {
    __shared__ float ub[4096];
    __shared__ float red[8], red2[8], stats[2];
    int row = blockIdx.x, tid = threadIdx.x;
    float s = 0.f, ss = 0.f;
    for (int c = tid; c < W; c += 256) {
        float v = b2f(u[(size_t)row * W + c]);
        ub[c] = v; s += v; ss += v * v;
    }
    #pragma unroll
    for (int off = 32; off; off >>= 1) { s += __shfl_xor(s, off); ss += __shfl_xor(ss, off); }
    int wave = tid >> 6, lane = tid & 63;
    if (lane == 0) { red[wave] = s; red2[wave] = ss; }
    __syncthreads();
    if (tid == 0) {
        float S = 0.f, SS = 0.f;
        for (int w2 = 0; w2 < 4; ++w2) { S += red[w2]; SS += red2[w2]; }
        float mu = S / W;
        stats[0] = mu;
        stats[1] = rsqrtf(SS / W - mu * mu + 1e-5f);
    }
    __syncthreads();
    float mu = stats[0], rs = stats[1];
    for (int c = tid; c < W; c += 256) {
        float v = (ub[c] - mu) * rs * g[c] + be[c];
        float y = 0.5f * v * (1.f + erff(v * 0.70710678118654752f));
        if (RES) y += resid[(size_t)row * W + c];
        if (OUT_F32) ((float*)out)[(size_t)row * W + c] = y;
        else         ((u16*)out)[(size_t)row * W + c] = f2b(y);
    }
}

// ---------------------------------------------------------------------------
// Qaug[B,H,S,128]: [0:64]=Q/8, [64:128]=lam*(tanh(Q)@J[h]).
// ---------------------------------------------------------------------------
__global__ __launch_bounds__(256) void aug_q_k(const u16* __restrict__ QKV,
                                               const float* __restrict__ J,
                                               const float* __restrict__ lamp,
                                               u16* __restrict__ QA) {
    __shared__ float Jl[64][68];
    __shared__ float Tq[64][65];
    int blk = blockIdx.x;
    int bh = blk >> 4, st = blk & 15;
    int b = bh >> 4, h = bh & 15;
    int s0 = st * 64;
    int tid = threadIdx.x;
    float lam = lamp[0];

    for (int i = tid; i < 4096; i += 256)
        Jl[i >> 6][i & 63] = J[h * 4096 + i];
    for (int i = tid; i < 4096; i += 256) {
        int r = i >> 6, c = i & 63;
        float v  = b2f(QKV[(size_t)(b * S_ + s0 + r) * QKVW + h * 64 + c]);
        Tq[r][c] = ftanh(v);
        QA[((size_t)(bh * S_ + s0 + r)) * 128 + c] = f2b(v * 0.125f);  // /sqrt(64)
    }
    __syncthreads();

    int r = tid >> 2, c0 = (tid & 3) * 16;
    float acc[16];
    #pragma unroll
    for (int j = 0; j < 16; ++j) acc[j] = 0.f;
    for (int k = 0; k < 64; ++k) {
        float a = Tq[r][k];
        #pragma unroll
        for (int j4 = 0; j4 < 4; ++j4) {
            float4 jv = *(const float4*)&Jl[k][c0 + j4 * 4];
            acc[j4 * 4 + 0] += a * jv.x;
            acc[j4 * 4 + 1] += a * jv.y;
            acc[j4 * 4 + 2] += a * jv.z;
            acc[j4 * 4 + 3] += a * jv.w;
        }
    }
    size_t orow = ((size_t)(bh * S_ + s0 + r)) * 128 + 64 + c0;
    #pragma unroll
    for (int j = 0; j < 16; ++j) QA[orow + j] = f2b(lam * acc[j]);
}

// Kaug[B,H,S,128]: [0:64]=K, [64:128]=tanh(K).
__global__ __launch_bounds__(256) void aug_k_k(const u16* __restrict__ QKV,
                                               u16* __restrict__ KA) {
    int idx = blockIdx.x * 256 + threadIdx.x;  // < B*S*D
    int d = idx & (D_ - 1);
    int bs = idx >> 10;
    int h = d >> 6, hd = d & 63;
    int b = bs >> 10, si = bs & (S_ - 1);
    u16 v      = QKV[(size_t)bs * QKVW + 1024 + d];
    size_t row = (size_t)((b * H_ + h) * S_ + si);
    KA[row * 128 + hd]      = v;
    KA[row * 128 + 64 + hd] = f2b(ftanh(b2f(v)));
}

// ---------------------------------------------------------------------------
// vt_k: V^T precompute. VT[bh][d(64)][s(S)] = V[b][s][h*64+d].
// LDS-tiled 64x64 transpose, coalesced read AND write. ~32 MB traffic.
// ---------------------------------------------------------------------------
__global__ __launch_bounds__(256) void vt_k(const u16* __restrict__ QKV,
                                            u16* __restrict__ VT) {
    __shared__ u16 L[64][72];
    int blk = blockIdx.x;
    int bh = blk >> 4, st = blk & 15;
    int b = bh >> 4, h = bh & 15;
    int s0 = st * 64;
    int tid = threadIdx.x;
    #pragma unroll
    for (int p = 0; p < 2; ++p) {
        int i = p * 2048 + tid * 8;
        int r = i >> 6, c = i & 63;   // r = s-in-tile, c = d
        uint4 v = *(const uint4*)&QKV[((size_t)(b * S_ + s0 + r)) * QKVW + 2048 + h * 64 + c];
        *(uint4*)&L[r][c] = v;
    }
    __syncthreads();
    #pragma unroll
    for (int p = 0; p < 2; ++p) {
        int i = p * 2048 + tid * 8;
        int d = i >> 6, s = i & 63;
        u16 o[8];
        #pragma unroll
        for (int j = 0; j < 8; ++j) o[j] = L[s + j][d];
        *(uint4*)&VT[((size_t)(bh * 64 + d)) * S_ + s0 + s] = *(uint4*)o;
    }
}

// ---------------------------------------------------------------------------
// MFMA flash attention, async-staged.
// K from KA [bh*S+key][128] and V^T from VT [bh*64+d][S], both staged with
// global_load_lds + chunk-XOR swizzle (chunk c of row R holds global chunk
// c^(R&7); reads XOR the same key — both-sides involution, rule #21).
// Double-buffered (2 slots, 2 barriers/kt): stage kt+1 at top (slot read
// in iter kt-1, retired before iter kt-1's closing lgkmcnt(0)+barrier);
// counted vmcnt(6) keeps tile kt+1's 6 loads in flight across compute.
// Q fragments hoisted out of the kt loop.
// ---------------------------------------------------------------------------
#define QS_STRIDE 136
#define PS_STRIDE 72
__global__ __launch_bounds__(256) void attn_k(const u16* __restrict__ QA,
                                              const u16* __restrict__ KA,
                                              const u16* __restrict__ VT,
                                              u16* __restrict__ out) {
    __shared__ u16 Qs[64 * QS_STRIDE];
    __shared__ u16 Ks[2][64 * 128];
    __shared__ u16 Vs[2][64 * 64];
    __shared__ u16 Ps[64 * PS_STRIDE];

    const int tid  = threadIdx.x;
    const int w    = tid >> 6, lane = tid & 63;
    const int q    = lane >> 4, mr = lane & 15;
    const int bh   = blockIdx.x >> 4;
    const int qt   = blockIdx.x & 15;

    #pragma unroll
    for (int p = 0; p < 4; ++p) {
        int idx = p * 2048 + tid * 8;
        int row = idx >> 7, col = idx & 127;
        uint4 v4 = *(const uint4*)&QA[((size_t)(bh * S_ + qt * 64 + row)) * 128 + col];
        *(uint4*)&Qs[row * QS_STRIDE + col] = v4;
    }

// K: wave w stages rows w*16+i*4+(lane>>4), i=0..3 (4 rows per GLDS16)
// V: wave w stages rows w*16+i*8+(lane>>3), i=0..1 (8 rows per GLDS16)
#define STAGEKV(pp, kt) do { \
        _Pragma("unroll") \
        for (int i = 0; i < 4; ++i) { \
            int R = w * 16 + i * 4 + (lane >> 4); \
            GLDS16(KA + ((size_t)(bh * S_ + (kt) * 64 + R)) * 128 + 8 * ((lane & 15) ^ (R & 7)), \
                   &Ks[pp][(w * 16 + i * 4) * 128]); \
        } \
        _Pragma("unroll") \
        for (int i = 0; i < 2; ++i) { \
            int Rv = w * 16 + i * 8 + (lane >> 3); \
            GLDS16(VT + ((size_t)(bh * 64 + Rv)) * S_ + (kt) * 64 + 8 * ((lane & 7) ^ (Rv & 7)), \
                   &Vs[pp][(w * 16 + i * 8) * 64]); \
        } \
    } while (0)

    STAGEKV(0, 0);
    __syncthreads();   // Q staged (cross-wave rows)

    bhalf8 afr[4];
    #pragma unroll
    for (int ks = 0; ks < 4; ++ks)
        afr[ks] = *(const bhalf8*)&Qs[(w * 16 + mr) * QS_STRIDE + ks * 32 + q * 8];

    fx4 zero = {0.f, 0.f, 0.f, 0.f};
    fx4 O[4] = {zero, zero, zero, zero};
    float m[4]  = {-3e38f, -3e38f, -3e38f, -3e38f};
    float l[4]  = {0.f, 0.f, 0.f, 0.f};

    int p = 0;
    for (int kt = 0; kt < 16; ++kt) {
        if (kt + 1 < 16) {
            STAGEKV(p ^ 1, kt + 1);
            waitvm<6>();
        } else {
            waitvm<0>();
        }
        __builtin_amdgcn_sched_barrier(0);
        __builtin_amdgcn_s_barrier();
        __builtin_amdgcn_sched_barrier(0);

        fx4 St[4] = {zero, zero, zero, zero};
        __builtin_amdgcn_s_setprio(1);
        #pragma unroll
        for (int nt = 0; nt < 4; ++nt) {
            #pragma unroll
            for (int ks = 0; ks < 4; ++ks) {
                bhalf8 bf = *(const bhalf8*)&Ks[p][(nt * 16 + mr) * 128 + 8 * (((ks * 4 + q) ^ (mr & 7)))];
                St[nt] = __builtin_amdgcn_mfma_f32_16x16x32_bf16(afr[ks], bf, St[nt], 0, 0, 0);
            }
        }
        __builtin_amdgcn_s_setprio(0);

        float alpha[4];
        #pragma unroll
        for (int r = 0; r < 4; ++r) {
            float mx = fmaxf(fmaxf(St[0][r], St[1][r]), fmaxf(St[2][r], St[3][r]));
            #pragma unroll
            for (int off = 8; off; off >>= 1) mx = fmaxf(mx, __shfl_xor(mx, off));
            float nm = fmaxf(m[r], mx);
            alpha[r] = __expf(m[r] - nm);
            m[r] = nm;
            float ps = 0.f;
            #pragma unroll
            for (int nt = 0; nt < 4; ++nt) {
                float pv = __expf(St[nt][r] - nm);
                St[nt][r] = pv;
                ps += pv;
            }
            #pragma unroll
            for (int off = 8; off; off >>= 1) ps += __shfl_xor(ps, off);
            l[r] = l[r] * alpha[r] + ps;
        }
        #pragma unroll
        for (int nt = 0; nt < 4; ++nt) {
            #pragma unroll
            for (int r = 0; r < 4; ++r) {
                Ps[(w * 16 + q * 4 + r) * PS_STRIDE + nt * 16 + mr] = f2b(St[nt][r]);
                O[nt][r] *= alpha[r];
            }
        }

        __builtin_amdgcn_s_setprio(1);
        #pragma unroll
        for (int ks = 0; ks < 2; ++ks) {
            bhalf8 pa = *(const bhalf8*)&Ps[(w * 16 + mr) * PS_STRIDE + ks * 32 + q * 8];
            #pragma unroll
            for (int nt = 0; nt < 4; ++nt) {
                bhalf8 bf = *(const bhalf8*)&Vs[p][(nt * 16 + mr) * 64 + 8 * (((ks * 4 + q) ^ (mr & 7)))];
                O[nt] = __builtin_amdgcn_mfma_f32_16x16x32_bf16(pa, bf, O[nt], 0, 0, 0);
            }
        }
        __builtin_amdgcn_s_setprio(0);
        asm volatile("s_waitcnt lgkmcnt(0)" ::: "memory");
        __builtin_amdgcn_sched_barrier(0);
        __builtin_amdgcn_s_barrier();
        p ^= 1;
    }
#undef STAGEKV

    const int b = bh >> 4, h = bh & 15;
    #pragma unroll
    for (int nt = 0; nt < 4; ++nt) {
        int d = nt * 16 + mr;
        #pragma unroll
        for (int r = 0; r < 4; ++r) {
            int row = qt * 64 + w * 16 + q * 4 + r;
            out[((size_t)(b * S_ + row)) * D_ + h * 64 + d] = f2b(O[nt][r] / l[r]);
        }
    }
}

// ---------------------------------------------------------------------------
// Workspace (120 MB; ws_size >= 136 MB confirmed by R1-R3 dual2 behavior):
//   [  0, 40)  WB: bf16 weights TRANSPOSED [N,K] — live whole launch
//   [ 40, 48)  XN(1-2) -> AT(4-5) -> U2(8-9)
//   [ 48, 72)  QKV fused (2-4b) -> Hb[48,56)(6-7) + X2 f32[56,72)(5-9)
//   [ 72,104)  QA[72,88)+KA[88,104)(3-4) -> U1(7-9)
//   [104,120)  VT (4a-4b)
// ---------------------------------------------------------------------------
extern "C" void kernel_launch(void* const* d_in, const int* in_sizes, int n_in,
                              void* d_out, int out_size, void* d_ws, size_t ws_size,
                              hipStream_t stream) {
    const float* x      = (const float*)d_in[0];
    const float* wq     = (const float*)d_in[1];
    const float* bq     = (const float*)d_in[2];
    const float* wk     = (const float*)d_in[3];
    const float* bk     = (const float*)d_in[4];
    const float* wv     = (const float*)d_in[5];
    const float* bv     = (const float*)d_in[6];
    const float* wo     = (const float*)d_in[7];
    const float* bo     = (const float*)d_in[8];
    const float* Jattn  = (const float*)d_in[9];
    const float* lamA   = (const float*)d_in[10];
    const float* g_attn = (const float*)d_in[11];
    const float* b_attn = (const float*)d_in[12];
    const float* W1     = (const float*)d_in[13];
    const float* b1     = (const float*)d_in[14];
    const float* J1     = (const float*)d_in[15];
    const float* g1     = (const float*)d_in[17];
    const float* be1    = (const float*)d_in[18];
    const float* W2     = (const float*)d_in[19];
    const float* b2     = (const float*)d_in[20];
    const float* J2     = (const float*)d_in[21];
    const float* g2     = (const float*)d_in[23];
    const float* be2    = (const float*)d_in[24];
    const float* g_ffn  = (const float*)d_in[25];
    const float* b_ffn  = (const float*)d_in[26];
    float* out = (float*)d_out;
    (void)in_sizes; (void)n_in; (void)out_size; (void)ws_size;

    char* wsp = (char*)d_ws;
    const size_t MB = 1u << 20;
    u16* WB = (u16*)(wsp);
    const u16* qkvT = WB;
    const u16* woT  = WB + ((size_t)3 << 20);
    const u16* W1T  = WB + ((size_t)4 << 20);
    const u16* J1T  = WB + ((size_t)8 << 20);
    const u16* W2T  = WB + ((size_t)12 << 20);
    const u16* J2T  = WB + ((size_t)16 << 20);
    u16*   XN   = (u16*)(wsp + 40 * MB);
    u16*   AT   = (u16*)(wsp + 40 * MB);
    u16*   U2   = (u16*)(wsp + 40 * MB);
    u16*   QKVb = (u16*)(wsp + 48 * MB);
    u16*   Hb   = (u16*)(wsp + 48 * MB);
    float* X2   = (float*)(wsp + 56 * MB);
    u16*   QA   = (u16*)(wsp + 72 * MB);
    u16*   KA   = (u16*)(wsp + 88 * MB);
    u16*   U1   = (u16*)(wsp + 72 * MB);
    u16*   VT   = (u16*)(wsp + 104 * MB);

    dim3 blk(256), blk5(512);
    // 0) weights f32 -> bf16, transposed to [N,K]
    cvt_t_k<<<5120, blk, 0, stream>>>(wq, wk, wv, wo, W1, J1, W2, J2, WB);
    // 1) attention pre-norm
    ln_k<<<NTOK, blk, 0, stream>>>(x, g_attn, b_attn, XN, D_);
    // 2) fused QKV projection [NTOK,3072]
    gemmP<128, 128, 64, 32, 0, true><<<(QKVW / 128) * (NTOK / 128), blk5, 0, stream>>>(
        XN, qkvT, bq, bk, bv, nullptr, QKVb, NTOK, QKVW, D_);
    // 3) augmented heads + V^T
    aug_q_k<<<B_ * H_ * (S_ / 64), blk, 0, stream>>>(QKVb, Jattn, lamA, QA);
    aug_k_k<<<(NTOK * D_) / 256, blk, 0, stream>>>(QKVb, KA);
    vt_k<<<B_ * H_ * (S_ / 64), blk, 0, stream>>>(QKVb, VT);
    // 4) MFMA flash attention (async-staged K/V)
    attn_k<<<B_ * H_ * (S_ / 64), blk, 0, stream>>>(QA, KA, VT, AT);
    // 5) output projection + residual -> f32 trunk X2
    gemmP<128, 128, 64, 32, 1, false><<<(D_ / 128) * (NTOK / 128), blk5, 0, stream>>>(
        AT, woT, bo, nullptr, nullptr, x, X2, NTOK, D_, D_);
    // 6) ffn pre-norm
    ln_k<<<NTOK, blk, 0, stream>>>(X2, g_ffn, b_ffn, Hb, D_);
    // 7) QBNN layer 1 (3-pass): W1 -> U1; tanh(Hb) in place; J1 RMW; LN+GELU
    gemmP<128, 128, 64, 32, 0, false><<<(FF_ / 128) * (NTOK / 128), blk5, 0, stream>>>(
        Hb, W1T, b1, nullptr, nullptr, nullptr, U1, NTOK, FF_, D_);
    tanh_k<<<(NTOK * D_) / 2048, blk, 0, stream>>>(Hb, Hb);
    gemmP<128, 128, 64, 32, 2, false><<<(FF_ / 128) * (NTOK / 128), blk5, 0, stream>>>(
        Hb, J1T, nullptr, nullptr, nullptr, nullptr, U1, NTOK, FF_, D_);
    lngelu_k<false, false><<<NTOK, blk, 0, stream>>>(U1, g1, be1, nullptr, U1, FF_);
    // 8) QBNN layer 2 (3-pass): W2 -> U2; tanh(U1) in place; J2 RMW
    gemmP<128, 128, 64, 32, 0, false><<<(D_ / 128) * (NTOK / 128), blk5, 0, stream>>>(
        U1, W2T, b2, nullptr, nullptr, nullptr, U2, NTOK, D_, FF_);
    tanh_k<<<(NTOK * FF_) / 2048, blk, 0, stream>>>(U1, U1);
    gemmP<128, 128, 64, 32, 2, false><<<(D_ / 128) * (NTOK / 128), blk5, 0, stream>>>(
        U1, J2T, nullptr, nullptr, nullptr, nullptr, U2, NTOK, D_, FF_);
    lngelu_k<true, true><<<NTOK, blk, 0, stream>>>(U2, g2, be2, X2, out, D_);
}

// Round 7
// 612.982 us; speedup vs baseline: 1.1693x; 1.0715x over previous
//
#include <hip/hip_runtime.h>
#include <cmath>

typedef unsigned short u16;
typedef unsigned int   u32;
typedef short bhalf8 __attribute__((ext_vector_type(8)));
typedef float fx4    __attribute__((ext_vector_type(4)));

#define B_   4
#define S_   1024
#define D_   1024
#define H_   16
#define HD_  64
#define FF_  4096
#define NTOK (B_*S_)
#define QKVW 3072
#define LOG2E 1.44269504088896f

__device__ __forceinline__ float b2f(u16 u) {
    u32 x = ((u32)u) << 16;
    return __uint_as_float(x);
}
__device__ __forceinline__ u16 f2b(float f) {
    u32 u = __float_as_uint(f);
    u32 r = (u + 0x7fffu + ((u >> 16) & 1u)) >> 16;
    return (u16)r;
}
// fast tanh: 1 - 2/(e^2x + 1); inf-safe at both ends
__device__ __forceinline__ float ftanh(float x) {
    float e = __expf(2.f * x);
    return 1.f - 2.f / (e + 1.f);
}
// raw v_exp_f32 = exp2
__device__ __forceinline__ float fexp2(float x) {
    float r;
    asm("v_exp_f32 %0, %1" : "=v"(r) : "v"(x));
    return r;
}

// async global->LDS, 16B per lane; LDS dest = wave-uniform base + lane*16
#define GLDS16(g, l) __builtin_amdgcn_global_load_lds( \
    (const __attribute__((address_space(1))) void*)(g), \
    (__attribute__((address_space(3))) void*)(l), 16, 0, 0)

template <int N> __device__ __forceinline__ void waitvm() {
    if constexpr (N == 8) asm volatile("s_waitcnt vmcnt(8)" ::: "memory");
    else if constexpr (N == 6) asm volatile("s_waitcnt vmcnt(6)" ::: "memory");
    else if constexpr (N == 4) asm volatile("s_waitcnt vmcnt(4)" ::: "memory");
    else if constexpr (N == 2) asm volatile("s_waitcnt vmcnt(2)" ::: "memory");
    else asm volatile("s_waitcnt vmcnt(0)" ::: "memory");
}

// ---------------------------------------------------------------------------
// Grid swizzle: XCD-chunked (bijective when nwg%8==0) + 8-row supertiles.
// ---------------------------------------------------------------------------
__device__ __forceinline__ void tile_swz(int gx, int gy, int& bx, int& by) {
    int bid = blockIdx.x;
    int nwg = gx * gy;
    if (((nwg | gy) & 7) == 0) {
        int chunk = nwg >> 3;
        int wg = (bid & 7) * chunk + (bid >> 3);
        int tps = gx << 3;
        int sup = wg / tps, rem = wg % tps;
        bx = rem >> 3;
        by = (sup << 3) + (rem & 7);
    } else {
        bx = bid % gx; by = bid / gx;
    }
}

// ---------------------------------------------------------------------------
// Weight convert + transpose: f32 [K,N] -> bf16 [N,K] tiles of 64x64.
// ---------------------------------------------------------------------------
__global__ __launch_bounds__(256) void cvt_t_k(const float* __restrict__ w0, const float* __restrict__ w1,
                                               const float* __restrict__ w2, const float* __restrict__ w3,
                                               const float* __restrict__ W1p, const float* __restrict__ J1p,
                                               const float* __restrict__ W2p, const float* __restrict__ J2p,
                                               u16* __restrict__ dst) {
    __shared__ u16 L[64][65];
    int bid = blockIdx.x, tid = threadIdx.x;
    const float* src; size_t dbase; int Kd, Nd, tk, tn;
    if (bid < 1024)      { int m = bid >> 8, t = bid & 255;
                           src = m == 0 ? w0 : m == 1 ? w1 : m == 2 ? w2 : w3;
                           dbase = (size_t)m << 20; Kd = 1024; Nd = 1024; tk = t >> 4; tn = t & 15; }
    else if (bid < 2048) { int t = bid - 1024; src = W1p; dbase = (size_t)4  << 20; Kd = 1024; Nd = 4096; tk = t >> 6; tn = t & 63; }
    else if (bid < 3072) { int t = bid - 2048; src = J1p; dbase = (size_t)8  << 20; Kd = 1024; Nd = 4096; tk = t >> 6; tn = t & 63; }
    else if (bid < 4096) { int t = bid - 3072; src = W2p; dbase = (size_t)12 << 20; Kd = 4096; Nd = 1024; tk = t >> 4; tn = t & 15; }
    else                 { int t = bid - 4096; src = J2p; dbase = (size_t)16 << 20; Kd = 4096; Nd = 1024; tk = t >> 4; tn = t & 15; }
    int k0 = tk * 64, n0 = tn * 64;
    int r = tid >> 2, c4 = (tid & 3) * 16;
    #pragma unroll
    for (int p = 0; p < 4; ++p) {
        float4 v = *(const float4*)&src[(size_t)(k0 + r) * Nd + n0 + c4 + p * 4];
        L[r][c4 + p * 4 + 0] = f2b(v.x);
        L[r][c4 + p * 4 + 1] = f2b(v.y);
        L[r][c4 + p * 4 + 2] = f2b(v.z);
        L[r][c4 + p * 4 + 3] = f2b(v.w);
    }
    __syncthreads();
    u16 o[16];
    #pragma unroll
    for (int j = 0; j < 16; ++j) o[j] = L[c4 + j][r];
    *(uint4*)&dst[dbase + (size_t)(n0 + r) * Kd + k0 + c4]     = *(uint4*)&o[0];
    *(uint4*)&dst[dbase + (size_t)(n0 + r) * Kd + k0 + c4 + 8] = *(uint4*)&o[8];
}

// elementwise tanh over bf16 buffer, 8 elems/thread (in-place safe) — fallback path
__global__ __launch_bounds__(256) void tanh_k(const u16* __restrict__ in, u16* __restrict__ outb) {
    size_t idx = ((size_t)blockIdx.x * 256 + threadIdx.x) * 8;
    uint4 v = *(const uint4*)&in[idx];
    const u16* p = (const u16*)&v;
    u16 o[8];
    #pragma unroll
    for (int j = 0; j < 8; ++j) o[j] = f2b(ftanh(b2f(p[j])));
    *(uint4*)&outb[idx] = *(uint4*)o;
}

// ---------------------------------------------------------------------------
// gemmP: 8-wave (512 thr) pipelined MFMA GEMM, 4-slot circular LDS buffer,
// prefetch depth 2, ONE barrier per K-step. BK=32. (Proven R5 structure.)
//   EPI 0: bf16(acc+bias)   EPI 1: f32(acc+bias+resid)
//   EPI 2: ht=Cout; Cout=bf16(ht+0.5*acc*ftanh(ht))   (fallback QBNN combine)
// ---------------------------------------------------------------------------
template <int BM, int BN, int WM, int WN, int EPI, bool SEG>
__global__ __launch_bounds__(512, 2) void gemmP(const u16* __restrict__ A,
                                                const u16* __restrict__ Bt,
                                                const float* __restrict__ bA,
                                                const float* __restrict__ bB,
                                                const float* __restrict__ bC,
                                                const float* __restrict__ resid,
                                                void* __restrict__ Cout,
                                                int M, int N, int K) {
    constexpr int IA = BM / 128;
    constexpr int IB = BN / 128;
    constexpr int NWN = BN / WN;
    constexpr int FM = WM / 16, FN = WN / 16;
    __shared__ u16 As[4][BM * 32];
    __shared__ u16 Bs[4][BN * 32];

    const int tid = threadIdx.x;
    const int w = tid >> 6, ln = tid & 63;
    const int q = ln >> 4, mr = ln & 15;
    const int wmi = w / NWN, wni = w % NWN;
    int bx, by;
    tile_swz(N / BN, M / BM, bx, by);
    const int m0 = by * BM, n0 = bx * BN;

    const int lr = ln >> 2;
    const int sc = 8 * ((ln & 3) ^ ((ln >> 3) & 3));
    const int qx8 = 8 * (q ^ ((mr >> 1) & 3));

    const u16* aA[IA];
    const u16* aB[IB];
    #pragma unroll
    for (int i = 0; i < IA; ++i)
        aA[i] = A + (size_t)(m0 + 16 * (w + 8 * i) + lr) * K + sc;
    #pragma unroll
    for (int i = 0; i < IB; ++i)
        aB[i] = Bt + (size_t)(n0 + 16 * (w + 8 * i) + lr) * K + sc;

    fx4 acc[FM][FN];
    #pragma unroll
    for (int i = 0; i < FM; ++i)
        #pragma unroll
        for (int j = 0; j < FN; ++j) acc[i][j] = (fx4){0.f, 0.f, 0.f, 0.f};

#define GP_STAGE(slot, kk) do { \
        _Pragma("unroll") \
        for (int i = 0; i < IA; ++i) GLDS16(aA[i] + (kk), &As[slot][(16 * (w + 8 * i)) * 32]); \
        _Pragma("unroll") \
        for (int i = 0; i < IB; ++i) GLDS16(aB[i] + (kk), &Bs[slot][(16 * (w + 8 * i)) * 32]); \
    } while (0)

    const int NT = K >> 5;
    GP_STAGE(0, 0);
    GP_STAGE(1, 32);
    for (int t = 0; t < NT; ++t) {
        if (t + 2 < NT) {
            GP_STAGE((t + 2) & 3, (t + 2) << 5);
            waitvm<2 * (IA + IB)>();
        } else if (t + 1 < NT) {
            waitvm<IA + IB>();
        } else {
            waitvm<0>();
        }
        asm volatile("s_waitcnt lgkmcnt(0)" ::: "memory");
        __builtin_amdgcn_sched_barrier(0);
        __builtin_amdgcn_s_barrier();
        __builtin_amdgcn_sched_barrier(0);

        const int sl = t & 3;
        bhalf8 afr[FM], bfr[FN];
        const u16* Ap = &As[sl][0];
        const u16* Bp = &Bs[sl][0];
        #pragma unroll
        for (int fm = 0; fm < FM; ++fm)
            afr[fm] = *(const bhalf8*)&Ap[(wmi * WM + fm * 16 + mr) * 32 + qx8];
        #pragma unroll
        for (int fn = 0; fn < FN; ++fn)
            bfr[fn] = *(const bhalf8*)&Bp[(wni * WN + fn * 16 + mr) * 32 + qx8];

        __builtin_amdgcn_s_setprio(1);
        #pragma unroll
        for (int fm = 0; fm < FM; ++fm)
            #pragma unroll
            for (int fn = 0; fn < FN; ++fn)
                acc[fm][fn] = __builtin_amdgcn_mfma_f32_16x16x32_bf16(afr[fm], bfr[fn], acc[fm][fn], 0, 0, 0);
        __builtin_amdgcn_s_setprio(0);
    }
#undef GP_STAGE

    #pragma unroll
    for (int fn = 0; fn < FN; ++fn) {
        int col = n0 + wni * WN + fn * 16 + mr;
        float bs;
        if (SEG) {
            const float* bp = col < 1024 ? bA : (col < 2048 ? bB : bC);
            bs = bp[col & 1023];
        } else {
            bs = bA ? bA[col] : 0.f;
        }
        #pragma unroll
        for (int fm = 0; fm < FM; ++fm) {
            #pragma unroll
            for (int r = 0; r < 4; ++r) {
                int row    = m0 + wmi * WM + fm * 16 + q * 4 + r;
                size_t idx = (size_t)row * N + col;
                float v    = acc[fm][fn][r] + bs;
                if (EPI == 0) {
                    ((u16*)Cout)[idx] = f2b(v);
                } else if (EPI == 1) {
                    ((float*)Cout)[idx] = v + resid[idx];
                } else {
                    float ht = b2f(((u16*)Cout)[idx]);
                    ((u16*)Cout)[idx] = f2b(ht + 0.5f * v * ftanh(ht));
                }
            }
        }
    }
}

// ---------------------------------------------------------------------------
// dgemmP: dual pipelined GEMM (QBNN W+J fused), same 4-slot/1-barrier/depth-2
// structure as gemmP but 4 streams (A, At=tanh(A), W, J). 128KB LDS, 16 MFMA
// per wave per K-step. Epilogue: ht=accW+bias; out=bf16(ht+0.5*accJ*tanh(ht)).
// BM=BN=128, 8 waves in 2x4 (WM=64, WN=32).
// ---------------------------------------------------------------------------
__global__ __launch_bounds__(512) void dgemmP(const u16* __restrict__ A,
                                              const u16* __restrict__ At,
                                              const u16* __restrict__ WT,
                                              const u16* __restrict__ JT,
                                              const float* __restrict__ bias,
                                              u16* __restrict__ Cout,
                                              int M, int N, int K) {
    __shared__ u16 As[4][128 * 32];
    __shared__ u16 Ts[4][128 * 32];
    __shared__ u16 Ws[4][128 * 32];
    __shared__ u16 Js[4][128 * 32];

    const int tid = threadIdx.x;
    const int w = tid >> 6, ln = tid & 63;
    const int q = ln >> 4, mr = ln & 15;
    const int wmi = w >> 2, wni = w & 3;
    int bx, by;
    tile_swz(N >> 7, M >> 7, bx, by);
    const int m0 = by * 128, n0 = bx * 128;

    const int lr = ln >> 2;
    const int sc = 8 * ((ln & 3) ^ ((ln >> 3) & 3));
    const int qx8 = 8 * (q ^ ((mr >> 1) & 3));

    const u16* aA = A  + (size_t)(m0 + 16 * w + lr) * K + sc;
    const u16* aT = At + (size_t)(m0 + 16 * w + lr) * K + sc;
    const u16* aW = WT + (size_t)(n0 + 16 * w + lr) * K + sc;
    const u16* aJ = JT + (size_t)(n0 + 16 * w + lr) * K + sc;

    fx4 aw[4][2], aj[4][2];
    #pragma unroll
    for (int i = 0; i < 4; ++i)
        #pragma unroll
        for (int j = 0; j < 2; ++j) {
            aw[i][j] = (fx4){0.f, 0.f, 0.f, 0.f};
            aj[i][j] = (fx4){0.f, 0.f, 0.f, 0.f};
        }

#define DG_STAGE(slot, kk) do { \
        GLDS16(aA + (kk), &As[slot][(16 * w) * 32]); \
        GLDS16(aT + (kk), &Ts[slot][(16 * w) * 32]); \
        GLDS16(aW + (kk), &Ws[slot][(16 * w) * 32]); \
        GLDS16(aJ + (kk), &Js[slot][(16 * w) * 32]); \
    } while (0)

    const int NT = K >> 5;
    DG_STAGE(0, 0);
    DG_STAGE(1, 32);
    for (int t = 0; t < NT; ++t) {
        if (t + 2 < NT) {
            DG_STAGE((t + 2) & 3, (t + 2) << 5);
            waitvm<8>();
        } else if (t + 1 < NT) {
            waitvm<4>();
        } else {
            waitvm<0>();
        }
        asm volatile("s_waitcnt lgkmcnt(0)" ::: "memory");
        __builtin_amdgcn_sched_barrier(0);
        __builtin_amdgcn_s_barrier();
        __builtin_amdgcn_sched_barrier(0);

        const int sl = t & 3;
        bhalf8 afr[4], tfr[4], bwf[2], bjf[2];
        #pragma unroll
        for (int fm = 0; fm < 4; ++fm) {
            afr[fm] = *(const bhalf8*)&As[sl][(wmi * 64 + fm * 16 + mr) * 32 + qx8];
            tfr[fm] = *(const bhalf8*)&Ts[sl][(wmi * 64 + fm * 16 + mr) * 32 + qx8];
        }
        #pragma unroll
        for (int fn = 0; fn < 2; ++fn) {
            bwf[fn] = *(const bhalf8*)&Ws[sl][(wni * 32 + fn * 16 + mr) * 32 + qx8];
            bjf[fn] = *(const bhalf8*)&Js[sl][(wni * 32 + fn * 16 + mr) * 32 + qx8];
        }

        __builtin_amdgcn_s_setprio(1);
        #pragma unroll
        for (int fm = 0; fm < 4; ++fm)
            #pragma unroll
            for (int fn = 0; fn < 2; ++fn) {
                aw[fm][fn] = __builtin_amdgcn_mfma_f32_16x16x32_bf16(afr[fm], bwf[fn], aw[fm][fn], 0, 0, 0);
                aj[fm][fn] = __builtin_amdgcn_mfma_f32_16x16x32_bf16(tfr[fm], bjf[fn], aj[fm][fn], 0, 0, 0);
            }
        __builtin_amdgcn_s_setprio(0);
    }
#undef DG_STAGE

    #pragma unroll
    for (int fn = 0; fn < 2; ++fn) {
        int col = n0 + wni * 32 + fn * 16 + mr;
        float bs = bias[col];
        #pragma unroll
        for (int fm = 0; fm < 4; ++fm) {
            #pragma unroll
            for (int r = 0; r < 4; ++r) {
                int row    = m0 + wmi * 64 + fm * 16 + q * 4 + r;
                size_t idx = (size_t)row * N + col;
                float ht   = aw[fm][fn][r] + bs;
                Cout[idx]  = f2b(ht + 0.5f * aj[fm][fn][r] * ftanh(ht));
            }
        }
    }
}

// ---------------------------------------------------------------------------
// LayerNorm over f32 input rows -> bf16 out. WT: also write tanh(ln).
// ---------------------------------------------------------------------------
template <bool WT>
__global__ __launch_bounds__(256) void ln_k(const float* __restrict__ xin,
                                            const float* __restrict__ g,
                                            const float* __restrict__ bb,
                                            u16* __restrict__ out,
                                            u16* __restrict__ tout, int W) {
    __shared__ float red[8], red2[8], stats[2];
    int row = blockIdx.x, tid = threadIdx.x;
    float s = 0.f, ss = 0.f;
    for (int c = tid; c < W; c += 256) {
        float v = xin[(size_t)row * W + c];
        s += v; ss += v * v;
    }
    #pragma unroll
    for (int off = 32; off; off >>= 1) { s += __shfl_xor(s, off); ss += __shfl_xor(ss, off); }
    int wave = tid >> 6, lane = tid & 63;
    if (lane == 0) { red[wave] = s; red2[wave] = ss; }
    __syncthreads();
    if (tid == 0) {
        float S = 0.f, SS = 0.f;
        for (int w2 = 0; w2 < 4; ++w2) { S += red[w2]; SS += red2[w2]; }
        float mu = S / W;
        stats[0] = mu;
        stats[1] = rsqrtf(SS / W - mu * mu + 1e-5f);
    }
    __syncthreads();
    float mu = stats[0], rs = stats[1];
    for (int c = tid; c < W; c += 256) {
        float v = (xin[(size_t)row * W + c] - mu) * rs * g[c] + bb[c];
        out[(size_t)row * W + c] = f2b(v);
        if (WT) tout[(size_t)row * W + c] = f2b(ftanh(v));
    }
}

// ---------------------------------------------------------------------------
// LN + exact GELU over bf16 rows u. RES: add f32 resid. OUT_F32: f32 out.
// WT: also write tanh(y).
// ---------------------------------------------------------------------------
template <bool RES, bool OUT_F32, bool WT>
__global__ __launch_bounds__(256) void lngelu_k(const u16* __restrict__ u,
                                                const float* __restrict__ g,
                                                const float* __restrict__ be,
                                                const float* __restrict__ resid,
                                                void* __restrict__ out,
                                                u16* __restrict__ tout, int W) {
    __shared__ float ub[4096];
    __shared__ float red[8], red2[8], stats[2];
    int row = blockIdx.x, tid = threadIdx.x;
    float s = 0.f, ss = 0.f;
    for (int c = tid; c < W; c += 256) {
        float v = b2f(u[(size_t)row * W + c]);
        ub[c] = v; s += v; ss += v * v;
    }
    #pragma unroll
    for (int off = 32; off; off >>= 1) { s += __shfl_xor(s, off); ss += __shfl_xor(ss, off); }
    int wave = tid >> 6, lane = tid & 63;
    if (lane == 0) { red[wave] = s; red2[wave] = ss; }
    __syncthreads();
    if (tid == 0) {
        float S = 0.f, SS = 0.f;
        for (int w2 = 0; w2 < 4; ++w2) { S += red[w2]; SS += red2[w2]; }
        float mu = S / W;
        stats[0] = mu;
        stats[1] = rsqrtf(SS / W - mu * mu + 1e-5f);
    }
    __syncthreads();
    float mu = stats[0], rs = stats[1];
    for (int c = tid; c < W; c += 256) {
        float v = (ub[c] - mu) * rs * g[c] + be[c];
        float y = 0.5f * v * (1.f + erff(v * 0.70710678118654752f));
        if (RES) y += resid[(size_t)row * W + c];
        if (OUT_F32) ((float*)out)[(size_t)row * W + c] = y;
        else         ((u16*)out)[(size_t)row * W + c] = f2b(y);
        if (WT) tout[(size_t)row * W + c] = f2b(ftanh(y));
    }
}

// ---------------------------------------------------------------------------
// Qaug[B,H,S,128]: [0:64]=Q*(log2e/8), [64:128]=lam*log2e*(tanh(Q)@J[h]).
// log2e folded in so attention softmax uses raw v_exp_f32 (exp2).
// ---------------------------------------------------------------------------
__global__ __launch_bounds__(256) void aug_q_k(const u16* __restrict__ QKV,
                                               const float* __restrict__ J,
                                               const float* __restrict__ lamp,
                                               u16* __restrict__ QA) {
    __shared__ float Jl[64][68];
    __shared__ float Tq[64][65];
    int blk = blockIdx.x;
    int bh = blk >> 4, st = blk & 15;
    int b = bh >> 4, h = bh & 15;
    int s0 = st * 64;
    int tid = threadIdx.x;
    float lam = lamp[0] * LOG2E;

    for (int i = tid; i < 4096; i += 256)
        Jl[i >> 6][i & 63] = J[h * 4096 + i];
    for (int i = tid; i < 4096; i += 256) {
        int r = i >> 6, c = i & 63;
        float v  = b2f(QKV[(size_t)(b * S_ + s0 + r) * QKVW + h * 64 + c]);
        Tq[r][c] = ftanh(v);
        QA[((size_t)(bh * S_ + s0 + r)) * 128 + c] = f2b(v * (0.125f * LOG2E));
    }
    __syncthreads();

    int r = tid >> 2, c0 = (tid & 3) * 16;
    float acc[16];
    #pragma unroll
    for (int j = 0; j < 16; ++j) acc[j] = 0.f;
    for (int k = 0; k < 64; ++k) {
        float a = Tq[r][k];
        #pragma unroll
        for (int j4 = 0; j4 < 4; ++j4) {
            float4 jv = *(const float4*)&Jl[k][c0 + j4 * 4];
            acc[j4 * 4 + 0] += a * jv.x;
            acc[j4 * 4 + 1] += a * jv.y;
            acc[j4 * 4 + 2] += a * jv.z;
            acc[j4 * 4 + 3] += a * jv.w;
        }
    }
    size_t orow = ((size_t)(bh * S_ + s0 + r)) * 128 + 64 + c0;
    #pragma unroll
    for (int j = 0; j < 16; ++j) QA[orow + j] = f2b(lam * acc[j]);
}

// Kaug[B,H,S,128]: [0:64]=K, [64:128]=tanh(K).
__global__ __launch_bounds__(256) void aug_k_k(const u16* __restrict__ QKV,
                                               u16* __restrict__ KA) {
    int idx = blockIdx.x * 256 + threadIdx.x;  // < B*S*D
    int d = idx & (D_ - 1);
    int bs = idx >> 10;
    int h = d >> 6, hd = d & 63;
    int b = bs >> 10, si = bs & (S_ - 1);
    u16 v      = QKV[(size_t)bs * QKVW + 1024 + d];
    size_t row = (size_t)((b * H_ + h) * S_ + si);
    KA[row * 128 + hd]      = v;
    KA[row * 128 + 64 + hd] = f2b(ftanh(b2f(v)));
}

// ---------------------------------------------------------------------------
// vt_k: V^T precompute. VT[bh][d(64)][s(S)] = V[b][s][h*64+d].
// ---------------------------------------------------------------------------
__global__ __launch_bounds__(256) void vt_k(const u16* __restrict__ QKV,
                                            u16* __restrict__ VT) {
    __shared__ u16 L[64][72];
    int blk = blockIdx.x;
    int bh = blk >> 4, st = blk & 15;
    int b = bh >> 4, h = bh & 15;
    int s0 = st * 64;
    int tid = threadIdx.x;
    #pragma unroll
    for (int p = 0; p < 2; ++p) {
        int i = p * 2048 + tid * 8;
        int r = i >> 6, c = i & 63;
        uint4 v = *(const uint4*)&QKV[((size_t)(b * S_ + s0 + r)) * QKVW + 2048 + h * 64 + c];
        *(uint4*)&L[r][c] = v;
    }
    __syncthreads();
    #pragma unroll
    for (int p = 0; p < 2; ++p) {
        int i = p * 2048 + tid * 8;
        int d = i >> 6, s = i & 63;
        u16 o[8];
        #pragma unroll
        for (int j = 0; j < 8; ++j) o[j] = L[s + j][d];
        *(uint4*)&VT[((size_t)(bh * 64 + d)) * S_ + s0 + s] = *(uint4*)o;
    }
}

// ---------------------------------------------------------------------------
// MFMA flash attention, async-staged (R5 structure) + exp2-domain softmax
// (log2e folded into QA) + defer-max (THR=8 log2 units -> P <= 256; skip
// alpha/rescale when per-tile max growth <= THR — T13).
// ---------------------------------------------------------------------------
#define QS_STRIDE 136
#define PS_STRIDE 72
__global__ __launch_bounds__(256) void attn_k(const u16* __restrict__ QA,
                                              const u16* __restrict__ KA,
                                              const u16* __restrict__ VT,
                                              u16* __restrict__ out) {
    __shared__ u16 Qs[64 * QS_STRIDE];
    __shared__ u16 Ks[2][64 * 128];
    __shared__ u16 Vs[2][64 * 64];
    __shared__ u16 Ps[64 * PS_STRIDE];

    const int tid  = threadIdx.x;
    const int w    = tid >> 6, lane = tid & 63;
    const int q    = lane >> 4, mr = lane & 15;
    const int bh   = blockIdx.x >> 4;
    const int qt   = blockIdx.x & 15;

    #pragma unroll
    for (int p = 0; p < 4; ++p) {
        int idx = p * 2048 + tid * 8;
        int row = idx >> 7, col = idx & 127;
        uint4 v4 = *(const uint4*)&QA[((size_t)(bh * S_ + qt * 64 + row)) * 128 + col];
        *(uint4*)&Qs[row * QS_STRIDE + col] = v4;
    }

#define STAGEKV(pp, kt) do { \
        _Pragma("unroll") \
        for (int i = 0; i < 4; ++i) { \
            int R = w * 16 + i * 4 + (lane >> 4); \
            GLDS16(KA + ((size_t)(bh * S_ + (kt) * 64 + R)) * 128 + 8 * ((lane & 15) ^ (R & 7)), \
                   &Ks[pp][(w * 16 + i * 4) * 128]); \
        } \
        _Pragma("unroll") \
        for (int i = 0; i < 2; ++i) { \
            int Rv = w * 16 + i * 8 + (lane >> 3); \
            GLDS16(VT + ((size_t)(bh * 64 + Rv)) * S_ + (kt) * 64 + 8 * ((lane & 7) ^ (Rv & 7)), \
                   &Vs[pp][(w * 16 + i * 8) * 64]); \
        } \
    } while (0)

    STAGEKV(0, 0);
    __syncthreads();

    bhalf8 afr[4];
    #pragma unroll
    for (int ks = 0; ks < 4; ++ks)
        afr[ks] = *(const bhalf8*)&Qs[(w * 16 + mr) * QS_STRIDE + ks * 32 + q * 8];

    fx4 zero = {0.f, 0.f, 0.f, 0.f};
    fx4 O[4] = {zero, zero, zero, zero};
    float m[4]  = {-3e38f, -3e38f, -3e38f, -3e38f};
    float l[4]  = {0.f, 0.f, 0.f, 0.f};

    int p = 0;
    for (int kt = 0; kt < 16; ++kt) {
        if (kt + 1 < 16) {
            STAGEKV(p ^ 1, kt + 1);
            waitvm<6>();
        } else {
            waitvm<0>();
        }
        __builtin_amdgcn_sched_barrier(0);
        __builtin_amdgcn_s_barrier();
        __builtin_amdgcn_sched_barrier(0);

        fx4 St[4] = {zero, zero, zero, zero};
        __builtin_amdgcn_s_setprio(1);
        #pragma unroll
        for (int nt = 0; nt < 4; ++nt) {
            #pragma unroll
            for (int ks = 0; ks < 4; ++ks) {
                bhalf8 bf = *(const bhalf8*)&Ks[p][(nt * 16 + mr) * 128 + 8 * (((ks * 4 + q) ^ (mr & 7)))];
                St[nt] = __builtin_amdgcn_mfma_f32_16x16x32_bf16(afr[ks], bf, St[nt], 0, 0, 0);
            }
        }
        __builtin_amdgcn_s_setprio(0);

        // row max (16-lane groups), defer-max decision (wave-uniform)
        float mx[4];
        float gmx = -3e38f;
        #pragma unroll
        for (int r = 0; r < 4; ++r) {
            float v = fmaxf(fmaxf(St[0][r], St[1][r]), fmaxf(St[2][r], St[3][r]));
            #pragma unroll
            for (int off = 8; off; off >>= 1) v = fmaxf(v, __shfl_xor(v, off));
            mx[r] = v;
            gmx = fmaxf(gmx, v - m[r]);
        }
        if (!__all(gmx <= 8.f)) {
            #pragma unroll
            for (int r = 0; r < 4; ++r) {
                float nm = fmaxf(m[r], mx[r]);
                float alpha = fexp2(m[r] - nm);
                m[r] = nm;
                l[r] *= alpha;
                #pragma unroll
                for (int nt = 0; nt < 4; ++nt) O[nt][r] *= alpha;
            }
        }
        #pragma unroll
        for (int r = 0; r < 4; ++r) {
            float ps = 0.f;
            #pragma unroll
            for (int nt = 0; nt < 4; ++nt) {
                float pv = fexp2(St[nt][r] - m[r]);
                St[nt][r] = pv;
                ps += pv;
            }
            #pragma unroll
            for (int off = 8; off; off >>= 1) ps += __shfl_xor(ps, off);
            l[r] += ps;
        }
        #pragma unroll
        for (int nt = 0; nt < 4; ++nt)
            #pragma unroll
            for (int r = 0; r < 4; ++r)
                Ps[(w * 16 + q * 4 + r) * PS_STRIDE + nt * 16 + mr] = f2b(St[nt][r]);

        __builtin_amdgcn_s_setprio(1);
        #pragma unroll
        for (int ks = 0; ks < 2; ++ks) {
            bhalf8 pa = *(const bhalf8*)&Ps[(w * 16 + mr) * PS_STRIDE + ks * 32 + q * 8];
            #pragma unroll
            for (int nt = 0; nt < 4; ++nt) {
                bhalf8 bf = *(const bhalf8*)&Vs[p][(nt * 16 + mr) * 64 + 8 * (((ks * 4 + q) ^ (mr & 7)))];
                O[nt] = __builtin_amdgcn_mfma_f32_16x16x32_bf16(pa, bf, O[nt], 0, 0, 0);
            }
        }
        __builtin_amdgcn_s_setprio(0);
        asm volatile("s_waitcnt lgkmcnt(0)" ::: "memory");
        __builtin_amdgcn_sched_barrier(0);
        __builtin_amdgcn_s_barrier();
        p ^= 1;
    }
#undef STAGEKV

    const int b = bh >> 4, h = bh & 15;
    #pragma unroll
    for (int nt = 0; nt < 4; ++nt) {
        int d = nt * 16 + mr;
        #pragma unroll
        for (int r = 0; r < 4; ++r) {
            int row = qt * 64 + w * 16 + q * 4 + r;
            out[((size_t)(b * S_ + row)) * D_ + h * 64 + d] = f2b(O[nt][r] / l[r]);
        }
    }
}

// ---------------------------------------------------------------------------
// Workspace (120 MB base; Ht2 region [104,136) used ONLY if ws_size>=136MB):
//   [  0, 40)  WB weights [N,K] bf16 — live whole launch
//   [ 40, 48)  XN(1-2) -> AT(4-5) -> Ht1(6-7) -> U2(8-9)
//   [ 48, 72)  QKV fused (2-4) -> Hb[48,56)(6-7) + X2 f32[56,72)(5-9)
//   [ 72,104)  QA[72,88)+KA[88,104)(3-4) -> U1(7-9)
//   [104,120)  VT (4)        [104,136) Ht2 (8, gated) — VT dead before Ht2
// ---------------------------------------------------------------------------
extern "C" void kernel_launch(void* const* d_in, const int* in_sizes, int n_in,
                              void* d_out, int out_size, void* d_ws, size_t ws_size,
                              hipStream_t stream) {
    const float* x      = (const float*)d_in[0];
    const float* wq     = (const float*)d_in[1];
    const float* bq     = (const float*)d_in[2];
    const float* wk     = (const float*)d_in[3];
    const float* bk     = (const float*)d_in[4];
    const float* wv     = (const float*)d_in[5];
    const float* bv     = (const float*)d_in[6];
    const float* wo     = (const float*)d_in[7];
    const float* bo     = (const float*)d_in[8];
    const float* Jattn  = (const float*)d_in[9];
    const float* lamA   = (const float*)d_in[10];
    const float* g_attn = (const float*)d_in[11];
    const float* b_attn = (const float*)d_in[12];
    const float* W1     = (const float*)d_in[13];
    const float* b1     = (const float*)d_in[14];
    const float* J1     = (const float*)d_in[15];
    const float* g1     = (const float*)d_in[17];
    const float* be1    = (const float*)d_in[18];
    const float* W2     = (const float*)d_in[19];
    const float* b2     = (const float*)d_in[20];
    const float* J2     = (const float*)d_in[21];
    const float* g2     = (const float*)d_in[23];
    const float* be2    = (const float*)d_in[24];
    const float* g_ffn  = (const float*)d_in[25];
    const float* b_ffn  = (const float*)d_in[26];
    float* out = (float*)d_out;
    (void)in_sizes; (void)n_in; (void)out_size;

    char* wsp = (char*)d_ws;
    const size_t MB = 1u << 20;
    u16* WB = (u16*)(wsp);
    const u16* qkvT = WB;
    const u16* woT  = WB + ((size_t)3 << 20);
    const u16* W1T  = WB + ((size_t)4 << 20);
    const u16* J1T  = WB + ((size_t)8 << 20);
    const u16* W2T  = WB + ((size_t)12 << 20);
    const u16* J2T  = WB + ((size_t)16 << 20);
    u16*   XN   = (u16*)(wsp + 40 * MB);
    u16*   AT   = (u16*)(wsp + 40 * MB);
    u16*   Ht1  = (u16*)(wsp + 40 * MB);
    u16*   U2   = (u16*)(wsp + 40 * MB);
    u16*   QKVb = (u16*)(wsp + 48 * MB);
    u16*   Hb   = (u16*)(wsp + 48 * MB);
    float* X2   = (float*)(wsp + 56 * MB);
    u16*   QA   = (u16*)(wsp + 72 * MB);
    u16*   KA   = (u16*)(wsp + 88 * MB);
    u16*   U1   = (u16*)(wsp + 72 * MB);
    u16*   VT   = (u16*)(wsp + 104 * MB);
    u16*   Ht2  = (u16*)(wsp + 104 * MB);
    const bool dual2 = ws_size >= 136 * MB;   // Ht2 needs [104,136)

    dim3 blk(256), blk5(512);
    // 0) weights f32 -> bf16, transposed to [N,K]
    cvt_t_k<<<5120, blk, 0, stream>>>(wq, wk, wv, wo, W1, J1, W2, J2, WB);
    // 1) attention pre-norm
    ln_k<false><<<NTOK, blk, 0, stream>>>(x, g_attn, b_attn, XN, nullptr, D_);
    // 2) fused QKV projection [NTOK,3072]
    gemmP<128, 128, 64, 32, 0, true><<<(QKVW / 128) * (NTOK / 128), blk5, 0, stream>>>(
        XN, qkvT, bq, bk, bv, nullptr, QKVb, NTOK, QKVW, D_);
    // 3) augmented heads + V^T
    aug_q_k<<<B_ * H_ * (S_ / 64), blk, 0, stream>>>(QKVb, Jattn, lamA, QA);
    aug_k_k<<<(NTOK * D_) / 256, blk, 0, stream>>>(QKVb, KA);
    vt_k<<<B_ * H_ * (S_ / 64), blk, 0, stream>>>(QKVb, VT);
    // 4) MFMA flash attention (async-staged K/V, exp2 softmax, defer-max)
    attn_k<<<B_ * H_ * (S_ / 64), blk, 0, stream>>>(QA, KA, VT, AT);
    // 5) output projection + residual -> f32 trunk X2
    gemmP<128, 128, 64, 32, 1, false><<<(D_ / 128) * (NTOK / 128), blk5, 0, stream>>>(
        AT, woT, bo, nullptr, nullptr, x, X2, NTOK, D_, D_);
    // 6) ffn pre-norm (+ tanh stream for dual GEMM)
    ln_k<true><<<NTOK, blk, 0, stream>>>(X2, g_ffn, b_ffn, Hb, Ht1, D_);
    // 7) QBNN layer 1: fused dual GEMM (W1 + J1 + combine)
    dgemmP<<<(FF_ / 128) * (NTOK / 128), blk5, 0, stream>>>(
        Hb, Ht1, W1T, J1T, b1, U1, NTOK, FF_, D_);
    // 8) QBNN layer 2: dual GEMM if Ht2 fits, else 3-pass fallback
    if (dual2) {
        lngelu_k<false, false, true><<<NTOK, blk, 0, stream>>>(U1, g1, be1, nullptr, U1, Ht2, FF_);
        dgemmP<<<(D_ / 128) * (NTOK / 128), blk5, 0, stream>>>(
            U1, Ht2, W2T, J2T, b2, U2, NTOK, D_, FF_);
    } else {
        lngelu_k<false, false, false><<<NTOK, blk, 0, stream>>>(U1, g1, be1, nullptr, U1, nullptr, FF_);
        gemmP<128, 128, 64, 32, 0, false><<<(D_ / 128) * (NTOK / 128), blk5, 0, stream>>>(
            U1, W2T, b2, nullptr, nullptr, nullptr, U2, NTOK, D_, FF_);
        tanh_k<<<(NTOK * FF_) / 2048, blk, 0, stream>>>(U1, U1);
        gemmP<128, 128, 64, 32, 2, false><<<(D_ / 128) * (NTOK / 128), blk5, 0, stream>>>(
            U1, J2T, nullptr, nullptr, nullptr, nullptr, U2, NTOK, D_, FF_);
    }
    lngelu_k<true, true, false><<<NTOK, blk, 0, stream>>>(U2, g2, be2, X2, out, nullptr, D_);
}